// Round 4
// baseline (354.619 us; speedup 1.0000x reference)
//
#include <hip/hip_runtime.h>
#include <math.h>

#define MT 16        // batch rows per block -> grid 1024 = exactly 4 blocks/CU
#define XS 152       // sX row stride (even for float2; 152%32=24 -> rows on distinct banks)
#define BSB 132      // sB row stride (even; 132%32=4 -> rows on distinct banks)
#define QS 66        // sQa row stride (even; 66%32=2 -> 16 action rows on distinct banks)

// ---------------------------------------------------------------------------
// card encoding: ce = [val_emb[v], suit_emb[s]] + [type_emb[ct], 0...]
// ---------------------------------------------------------------------------
__device__ __forceinline__ void encode_card32(int c,
                                              const float* __restrict__ val_emb,
                                              const float* __restrict__ suit_emb,
                                              const float* __restrict__ type_emb,
                                              float* e) {
  bool inv = (c == 0) || (c == 53);
  int v = inv ? 0 : ((c - 1) % 13 + 1);
  int s = inv ? 0 : ((c - 1) / 13 + 1);
  int ct = (v == 11) ? 1 : (v == 12) ? 2 : (v == 13) ? 3 : 0;
#pragma unroll
  for (int i = 0; i < 16; ++i) e[i] = val_emb[v * 16 + i];
#pragma unroll
  for (int i = 0; i < 16; ++i) e[16 + i] = suit_emb[s * 16 + i];
#pragma unroll
  for (int i = 0; i < 8; ++i) e[i] += type_emb[ct * 8 + i];
}

// ---------------------------------------------------------------------------
// 128-wide layer, LDS-staged weights in 16-row tiles (8 KB), (m,n)=(4,2) tiling:
// thread = (rg = tid&3 -> rows rg+4i, cg = tid>>2 -> cols cg*2, cg*2+1).
// Weight read: one ds_read_b64/kk covering all 32 banks exactly once (no conflicts).
// Act reads: float2 (2 kk), 4 distinct rows/instr on distinct banks.
// ---------------------------------------------------------------------------
template <int K, bool RELU>
__device__ __forceinline__ void layer128_lds(
    const float* __restrict__ actIn, int is, float* __restrict__ actOut, int os,
    const float* __restrict__ W, const float* __restrict__ bias,
    float* __restrict__ wbuf) {
  const int tid = threadIdx.x;
  const int rg = tid & 3;
  const int c0 = (tid >> 2) * 2;
  float2 acc0, acc1, acc2, acc3;
  {
    float2 bv = *(const float2*)&bias[c0];
    acc0 = bv; acc1 = bv; acc2 = bv; acc3 = bv;
  }
  constexpr int FT = K / 16;
  constexpr int TAIL = K - FT * 16;
#pragma unroll 1
  for (int t = 0; t < FT; ++t) {
    const int k0 = t * 16;
    __syncthreads();  // previous wbuf tile fully consumed
#pragma unroll
    for (int p = 0; p < 2; ++p) {
      int idx = tid * 4 + p * 1024;
      *(float4*)&wbuf[idx] = *(const float4*)&W[(size_t)k0 * 128 + idx];
    }
    __syncthreads();
#pragma unroll
    for (int kk = 0; kk < 16; kk += 2) {
      float2 w0 = *(const float2*)&wbuf[kk * 128 + c0];
      float2 w1 = *(const float2*)&wbuf[(kk + 1) * 128 + c0];
      float2 a0 = *(const float2*)&actIn[(rg + 0) * is + k0 + kk];
      float2 a1 = *(const float2*)&actIn[(rg + 4) * is + k0 + kk];
      float2 a2 = *(const float2*)&actIn[(rg + 8) * is + k0 + kk];
      float2 a3 = *(const float2*)&actIn[(rg + 12) * is + k0 + kk];
      acc0.x += a0.x * w0.x + a0.y * w1.x;  acc0.y += a0.x * w0.y + a0.y * w1.y;
      acc1.x += a1.x * w0.x + a1.y * w1.x;  acc1.y += a1.x * w0.y + a1.y * w1.y;
      acc2.x += a2.x * w0.x + a2.y * w1.x;  acc2.y += a2.x * w0.y + a2.y * w1.y;
      acc3.x += a3.x * w0.x + a3.y * w1.x;  acc3.y += a3.x * w0.y + a3.y * w1.y;
    }
  }
  if constexpr (TAIL > 0) {
    const int k0 = FT * 16;
    __syncthreads();
    for (int idx = tid * 4; idx < TAIL * 128; idx += 1024)
      *(float4*)&wbuf[idx] = *(const float4*)&W[(size_t)k0 * 128 + idx];
    __syncthreads();
#pragma unroll
    for (int kk = 0; kk < TAIL; kk += 2) {
      float2 w0 = *(const float2*)&wbuf[kk * 128 + c0];
      float2 w1 = *(const float2*)&wbuf[(kk + 1) * 128 + c0];
      float2 a0 = *(const float2*)&actIn[(rg + 0) * is + k0 + kk];
      float2 a1 = *(const float2*)&actIn[(rg + 4) * is + k0 + kk];
      float2 a2 = *(const float2*)&actIn[(rg + 8) * is + k0 + kk];
      float2 a3 = *(const float2*)&actIn[(rg + 12) * is + k0 + kk];
      acc0.x += a0.x * w0.x + a0.y * w1.x;  acc0.y += a0.x * w0.y + a0.y * w1.y;
      acc1.x += a1.x * w0.x + a1.y * w1.x;  acc1.y += a1.x * w0.y + a1.y * w1.y;
      acc2.x += a2.x * w0.x + a2.y * w1.x;  acc2.y += a2.x * w0.y + a2.y * w1.y;
      acc3.x += a3.x * w0.x + a3.y * w1.x;  acc3.y += a3.x * w0.y + a3.y * w1.y;
    }
  }
  if (RELU) {
    acc0.x = fmaxf(acc0.x, 0.f); acc0.y = fmaxf(acc0.y, 0.f);
    acc1.x = fmaxf(acc1.x, 0.f); acc1.y = fmaxf(acc1.y, 0.f);
    acc2.x = fmaxf(acc2.x, 0.f); acc2.y = fmaxf(acc2.y, 0.f);
    acc3.x = fmaxf(acc3.x, 0.f); acc3.y = fmaxf(acc3.y, 0.f);
  }
  *(float2*)&actOut[(rg + 0) * os + c0] = acc0;
  *(float2*)&actOut[(rg + 4) * os + c0] = acc1;
  *(float2*)&actOut[(rg + 8) * os + c0] = acc2;
  *(float2*)&actOut[(rg + 12) * os + c0] = acc3;
}

// ---------------------------------------------------------------------------
// Dual 64-wide layer: cols [0:64) = t1 = relu(ctx@atc_w1+b), [64:128) = P = ctx@as_w1[:128].
// Same (4,2) structure; wbuf row = [Wt row | Wp row].
// ---------------------------------------------------------------------------
__device__ __forceinline__ void layer_dual64(
    const float* __restrict__ actIn, int is, float* __restrict__ actOut, int os,
    const float* __restrict__ Wt, const float* __restrict__ bt,
    const float* __restrict__ Wp, float* __restrict__ wbuf) {
  const int tid = threadIdx.x;
  const int rg = tid & 3;
  const int c0 = (tid >> 2) * 2;
  const bool isT = (c0 < 64);
  float2 acc0, acc1, acc2, acc3;
  {
    float2 bv = isT ? *(const float2*)&bt[c0] : make_float2(0.f, 0.f);
    acc0 = bv; acc1 = bv; acc2 = bv; acc3 = bv;
  }
#pragma unroll 1
  for (int t = 0; t < 8; ++t) {
    const int k0 = t * 16;
    __syncthreads();
#pragma unroll
    for (int p = 0; p < 2; ++p) {
      int idx = tid * 4 + p * 1024;
      int row = idx >> 7, c = idx & 127;
      const float* src = (c < 64) ? &Wt[(size_t)(k0 + row) * 64 + c]
                                  : &Wp[(size_t)(k0 + row) * 64 + (c - 64)];
      *(float4*)&wbuf[idx] = *(const float4*)src;
    }
    __syncthreads();
#pragma unroll
    for (int kk = 0; kk < 16; kk += 2) {
      float2 w0 = *(const float2*)&wbuf[kk * 128 + c0];
      float2 w1 = *(const float2*)&wbuf[(kk + 1) * 128 + c0];
      float2 a0 = *(const float2*)&actIn[(rg + 0) * is + k0 + kk];
      float2 a1 = *(const float2*)&actIn[(rg + 4) * is + k0 + kk];
      float2 a2 = *(const float2*)&actIn[(rg + 8) * is + k0 + kk];
      float2 a3 = *(const float2*)&actIn[(rg + 12) * is + k0 + kk];
      acc0.x += a0.x * w0.x + a0.y * w1.x;  acc0.y += a0.x * w0.y + a0.y * w1.y;
      acc1.x += a1.x * w0.x + a1.y * w1.x;  acc1.y += a1.x * w0.y + a1.y * w1.y;
      acc2.x += a2.x * w0.x + a2.y * w1.x;  acc2.y += a2.x * w0.y + a2.y * w1.y;
      acc3.x += a3.x * w0.x + a3.y * w1.x;  acc3.y += a3.x * w0.y + a3.y * w1.y;
    }
  }
  if (isT) {
    acc0.x = fmaxf(acc0.x, 0.f); acc0.y = fmaxf(acc0.y, 0.f);
    acc1.x = fmaxf(acc1.x, 0.f); acc1.y = fmaxf(acc1.y, 0.f);
    acc2.x = fmaxf(acc2.x, 0.f); acc2.y = fmaxf(acc2.y, 0.f);
    acc3.x = fmaxf(acc3.x, 0.f); acc3.y = fmaxf(acc3.y, 0.f);
  }
  *(float2*)&actOut[(rg + 0) * os + c0] = acc0;
  *(float2*)&actOut[(rg + 4) * os + c0] = acc1;
  *(float2*)&actOut[(rg + 8) * os + c0] = acc2;
  *(float2*)&actOut[(rg + 12) * os + c0] = acc3;
}

// ---------------------------------------------------------------------------
// Fused kernel. 16 rows/block, 256 threads, grid 1024. LDS ~35.2 KB -> 4 blk/CU.
//   sX[r]: [0:32) hand_ctx | [32:64) enemy | [64:96) strat_ctx | [96:150) discard
//          later: GEMM ping buffer; finally [0:64) t1, [64:128) P
//   sB[r]: [0:20) strat_in | [20:84) t64 | [84:116) V ; later GEMM pong buffer
//   wbuf : action scratch, then 16-row weight tiles, finally as_w2 (64x32)
//   sQa[30][66], sMeta: strength/hasv/w3/b2
// ---------------------------------------------------------------------------
__global__ __launch_bounds__(256, 4) void policy_fused(
    const int* __restrict__ hand_cards, const int* __restrict__ enemy_card,
    const int* __restrict__ hand_size, const float* __restrict__ game_state,
    const float* __restrict__ discard, const int* __restrict__ acards,
    const float* __restrict__ val_emb, const float* __restrict__ suit_emb,
    const float* __restrict__ type_emb,
    const float* __restrict__ ce_w1, const float* __restrict__ ce_b1,
    const float* __restrict__ ce_w2, const float* __restrict__ ce_b2,
    const float* __restrict__ he_wv, const float* __restrict__ he_bv,
    const float* __restrict__ he_wo, const float* __restrict__ he_bo,
    const float* __restrict__ se_w1, const float* __restrict__ se_b1,
    const float* __restrict__ se_w2, const float* __restrict__ se_b2,
    const float* __restrict__ atc_w1, const float* __restrict__ atc_b1,
    const float* __restrict__ atc_w2, const float* __restrict__ atc_b2,
    const float* __restrict__ as_w1, const float* __restrict__ as_b1,
    const float* __restrict__ as_w2, const float* __restrict__ as_b2,
    const float* __restrict__ as_w3, const float* __restrict__ as_b3,
    const float* __restrict__ cx_w1, const float* __restrict__ cx_b1,
    const float* __restrict__ cx_w2, const float* __restrict__ cx_b2,
    const float* __restrict__ cx_w3, const float* __restrict__ cx_b3,
    float* __restrict__ out) {
  __shared__ float sX[MT * XS];      // 9728 B
  __shared__ float sB[MT * BSB];     // 8448 B
  __shared__ float wbuf[2048];       // 8192 B
  __shared__ float sQa[30 * QS];     // 7920 B
  __shared__ float sMeta[128];       // 512 B
  __shared__ float sTp[MT * 4];
  __shared__ float sLen[MT];

  const int tid = threadIdx.x;
  const int b0 = blockIdx.x * MT;

  // ---------------- P0: global gathers + per-row features + action features --
  for (int idx = tid; idx < MT * 54; idx += 256) {
    int r = idx / 54, k = idx - r * 54;
    sX[r * XS + 96 + k] = discard[(size_t)b0 * 54 + idx];
  }
  for (int idx = tid; idx < MT * 10; idx += 256) {
    int r = idx / 10, k = idx - r * 10;
    sB[r * BSB + k] = game_state[(size_t)b0 * 10 + idx];
  }
  if (tid < MT) {
    const int b = b0 + tid;
    const float hsz = (float)hand_size[b];
    sLen[tid] = 8.0f / fmaxf(hsz, 1.0f);
    int aces = 0, faces = 0, low = 0, c1 = 0, c2 = 0, c3 = 0, c4 = 0;
#pragma unroll
    for (int i = 0; i < 8; ++i) {
      int c = hand_cards[b * 8 + i];
      int v = (c == 0) ? 0 : ((c - 1) % 13 + 1);
      int s = (c == 0) ? 0 : ((c - 1) / 13 + 1);
      aces += (v == 1);
      faces += (v >= 11 && v <= 13);
      low += (v >= 2 && v <= 6);
      c1 += (s == 1); c2 += (s == 2); c3 += (s == 3); c4 += (s == 4);
    }
    float sdiv = (float)((c1 > 0) + (c2 > 0) + (c3 > 0) + (c4 > 0)) * 0.25f;
    float hvr = (float)faces / (hsz + 1e-8f);
    float* si = &sB[tid * BSB];
    si[10] = hsz; si[11] = (float)aces; si[12] = (float)faces;
    si[13] = (float)low; si[14] = (float)c1; si[15] = (float)c2;
    si[16] = (float)c3; si[17] = (float)c4; si[18] = hvr; si[19] = sdiv;
    float e[32];
    encode_card32(enemy_card[b], val_emb, suit_emb, type_emb, e);
#pragma unroll
    for (int i = 0; i < 32; ++i) sX[tid * XS + 32 + i] = e[i];
  }
  if (tid < 30) {  // action features -> wbuf scratch + sMeta
    int c[4];
#pragma unroll
    for (int i = 0; i < 4; ++i) c[i] = acards[tid * 4 + i];
    bool mask[4]; int vals[4], suits[4]; int csize = 0; bool hasv = false;
#pragma unroll
    for (int i = 0; i < 4; ++i) {
      mask[i] = (c[i] != 0);
      if (mask[i]) { csize++; hasv = true; }
      vals[i] = mask[i] ? ((c[i] - 1) % 13 + 1) : 0;
      suits[i] = mask[i] ? ((c[i] - 1) / 13 + 1) : 0;
    }
    int fvv = mask[0] ? vals[0] : mask[1] ? vals[1] : mask[2] ? vals[2]
              : mask[3] ? vals[3] : vals[0];
    bool same = true;
#pragma unroll
    for (int i = 0; i < 4; ++i) if (mask[i] && vals[i] != fvv) same = false;
    float total = 0.f;
#pragma unroll
    for (int i = 0; i < 4; ++i) {
      if (mask[i]) {
        int v = vals[i];
        total += (v == 1) ? 1.f : (v == 11) ? 10.f : (v == 12) ? 15.f
                 : (v == 13) ? 20.f : (float)v;
      }
    }
    float uniq = 0.f;
#pragma unroll
    for (int s = 1; s <= 4; ++s) {
      bool any = false;
#pragma unroll
      for (int i = 0; i < 4; ++i) if (suits[i] == s) any = true;
      uniq += any ? 1.f : 0.f;
    }
    bool ace = false;
#pragma unroll
    for (int i = 0; i < 4; ++i) if (mask[i] && vals[i] == 1) ace = true;
    float f_same = same ? 1.f : 0.f, f_ace = ace ? 1.f : 0.f;
    float valid = (((float)csize <= 4.f) && (f_same > 0.f || f_ace > 0.f)) ? 1.f : 0.f;
    float feats[6] = {(float)csize, f_same, total, uniq, f_ace, valid};
    if (!hasv) { for (int i = 0; i < 6; ++i) feats[i] = 0.f; }
    float emb[32];
#pragma unroll
    for (int i = 0; i < 32; ++i) emb[i] = 0.f;
    float cnt = 0.f;
#pragma unroll
    for (int i = 0; i < 4; ++i) {
      float e[32];
      encode_card32(c[i], val_emb, suit_emb, type_emb, e);
      if (mask[i]) {
#pragma unroll
        for (int j = 0; j < 32; ++j) emb[j] += e[j];
        cnt += 1.f;
      }
    }
    float invc = 1.f / fmaxf(cnt, 1.f);
#pragma unroll
    for (int j = 0; j < 32; ++j)
      wbuf[tid * 32 + j] = hasv ? emb[j] * invc : 0.f;     // act_emb scratch
    float t32[32];
#pragma unroll
    for (int j = 0; j < 32; ++j) {
      float acc = ce_b1[j];
#pragma unroll
      for (int k = 0; k < 6; ++k) acc += feats[k] * ce_w1[k * 32 + j];
      t32[j] = fmaxf(acc, 0.f);
    }
#pragma unroll
    for (int j = 0; j < 16; ++j) {
      float acc = ce_b2[j];
#pragma unroll
      for (int k = 0; k < 32; ++k) acc += t32[k] * ce_w2[k * 16 + j];
      wbuf[960 + tid * 16 + j] = acc;                      // combo scratch
    }
    sMeta[tid] = feats[2] * 0.05f;       // strength
    sMeta[32 + tid] = hasv ? 1.f : 0.f;  // has_valid
  }
  if (tid < 32) {
    sMeta[64 + tid] = as_w3[tid];
    sMeta[96 + tid] = as_b2[tid];
  }
  __syncthreads();

  // ---------------- P1: Qa (wbuf scratch -> sQa); se L1 ---------------------
  for (int idx = tid; idx < 1920; idx += 256) {
    int a = idx >> 6, j = idx & 63;
    float acc = as_b1[j];
#pragma unroll
    for (int k = 0; k < 32; ++k) acc += wbuf[a * 32 + k] * as_w1[(128 + k) * 64 + j];
#pragma unroll
    for (int k = 0; k < 16; ++k) acc += wbuf[960 + a * 16 + k] * as_w1[(160 + k) * 64 + j];
    sQa[a * QS + j] = acc;
  }
  {
    const int r = tid >> 4, j0 = (tid & 15) * 4;
    float acc[4];
#pragma unroll
    for (int j = 0; j < 4; ++j) acc[j] = se_b1[j0 + j];
    for (int k = 0; k < 20; ++k) {
      float a = sB[r * BSB + k];
#pragma unroll
      for (int j = 0; j < 4; ++j) acc[j] += a * se_w1[k * 64 + j0 + j];
    }
#pragma unroll
    for (int j = 0; j < 4; ++j) sB[r * BSB + 20 + j0 + j] = fmaxf(acc[j], 0.f);
  }
  __syncthreads();

  // ---------------- P2: se L2 64->32 -> sX[64:96) ; V = enemy@wv -> sB[84:116)
  {
    const int r = tid >> 4, j0 = (tid & 15) * 2;
    float acc[2] = {se_b2[j0], se_b2[j0 + 1]};
    for (int k = 0; k < 64; ++k) {
      float a = sB[r * BSB + 20 + k];
      acc[0] += a * se_w2[k * 32 + j0];
      acc[1] += a * se_w2[k * 32 + j0 + 1];
    }
    sX[r * XS + 64 + j0] = acc[0];
    sX[r * XS + 64 + j0 + 1] = acc[1];
    float vacc[2] = {he_bv[j0], he_bv[j0 + 1]};
    for (int k = 0; k < 32; ++k) {
      float a = sX[r * XS + 32 + k];
      vacc[0] += a * he_wv[k * 32 + j0];
      vacc[1] += a * he_wv[k * 32 + j0 + 1];
    }
    sB[r * BSB + 84 + j0] = vacc[0];
    sB[r * BSB + 84 + j0 + 1] = vacc[1];
  }
  __syncthreads();

  // ---------------- P3: hand_ctx = (V@wo + bo) * 8/len -> sX[0:32) ----------
  {
    const int r = tid >> 4, j0 = (tid & 15) * 2;
    float acc[2] = {he_bo[j0], he_bo[j0 + 1]};
    for (int k = 0; k < 32; ++k) {
      float a = sB[r * BSB + 84 + k];
      acc[0] += a * he_wo[k * 32 + j0];
      acc[1] += a * he_wo[k * 32 + j0 + 1];
    }
    float scale = sLen[r];
    sX[r * XS + j0] = scale * acc[0];
    sX[r * XS + j0 + 1] = scale * acc[1];
  }
  // no barrier needed: each layer's leading stage-barrier orders these writes

  // ---------------- P4..P6: context MLP chain (LDS-staged weights) ----------
  layer128_lds<150, true>(sX, XS, sB, BSB, cx_w1, cx_b1, wbuf);
  layer128_lds<128, true>(sB, BSB, sX, XS, cx_w2, cx_b2, wbuf);
  layer128_lds<128, false>(sX, XS, sB, BSB, cx_w3, cx_b3, wbuf);

  // ---------------- P7: t1 | P from ctx (dual staged layer) -----------------
  layer_dual64(sB, BSB, sX, XS, atc_w1, atc_b1, as_w1, wbuf);
  __syncthreads();

  // overlay as_w2 into wbuf (visible by P8's barrier)
#pragma unroll
  for (int p = 0; p < 2; ++p) {
    int idx = tid * 4 + p * 1024;
    *(float4*)&wbuf[idx] = *(const float4*)&as_w2[idx];
  }

  // ---------------- P8: type logits + softmax -------------------------------
  if (tid < MT * 4) {
    const int r = tid >> 2, j = tid & 3;
    float acc = atc_b2[j];
    for (int k = 0; k < 64; ++k) acc += sX[r * XS + k] * atc_w2[k * 4 + j];
    sTp[r * 4 + j] = acc;
  }
  __syncthreads();
  if (tid < MT) {
    float l0 = sTp[tid * 4 + 0], l1 = sTp[tid * 4 + 1];
    float l2 = sTp[tid * 4 + 2], l3 = sTp[tid * 4 + 3];
    float m = fmaxf(fmaxf(l0, l1), fmaxf(l2, l3));
    float e0 = expf(l0 - m), e1 = expf(l1 - m), e2 = expf(l2 - m), e3 = expf(l3 - m);
    float inv = 1.f / (e0 + e1 + e2 + e3);
    sTp[tid * 4 + 0] = e0 * inv; sTp[tid * 4 + 1] = e1 * inv;
    sTp[tid * 4 + 2] = e2 * inv; sTp[tid * 4 + 3] = e3 * inv;
  }
  __syncthreads();

  // ---------------- P9: scoring (16 rows x 30 actions; w2 from wbuf) --------
  {
    const int r = tid >> 4, a0 = tid & 15;
    const int a1 = a0 + 16;
    const bool v1 = (a1 < 30);
    const int A1 = v1 ? a1 : 0;
    const float b3v = as_b3[0];
    const float tp0 = sTp[r * 4 + 0], tp1 = sTp[r * 4 + 1], tp3 = sTp[r * 4 + 3];
    const float* Prow = &sX[r * XS + 64];
    const float* qa0 = &sQa[a0 * QS];
    const float* qa1 = &sQa[A1 * QS];
    float acc0[32], acc1[32];
#pragma unroll
    for (int j = 0; j < 32; ++j) { acc0[j] = 0.f; acc1[j] = 0.f; }
#pragma unroll 2
    for (int k = 0; k < 64; k += 2) {
      float2 p  = *(const float2*)&Prow[k];
      float2 q0 = *(const float2*)&qa0[k];
      float2 q1 = *(const float2*)&qa1[k];
      float s0a = fmaxf(p.x + q0.x, 0.f), s0b = fmaxf(p.y + q0.y, 0.f);
      float s1a = fmaxf(p.x + q1.x, 0.f), s1b = fmaxf(p.y + q1.y, 0.f);
#pragma unroll
      for (int j = 0; j < 32; j += 4) {
        float4 wA = *(const float4*)&wbuf[k * 32 + j];
        float4 wB = *(const float4*)&wbuf[(k + 1) * 32 + j];
        acc0[j + 0] += s0a * wA.x + s0b * wB.x;
        acc0[j + 1] += s0a * wA.y + s0b * wB.y;
        acc0[j + 2] += s0a * wA.z + s0b * wB.z;
        acc0[j + 3] += s0a * wA.w + s0b * wB.w;
        acc1[j + 0] += s1a * wA.x + s1b * wB.x;
        acc1[j + 1] += s1a * wA.y + s1b * wB.y;
        acc1[j + 2] += s1a * wA.z + s1b * wB.z;
        acc1[j + 3] += s1a * wA.w + s1b * wB.w;
      }
    }
    float sc0 = b3v, sc1 = b3v;
#pragma unroll
    for (int j = 0; j < 32; ++j) {
      float w3 = sMeta[64 + j], bb2 = sMeta[96 + j];
      sc0 += fmaxf(acc0[j] + bb2, 0.f) * w3;
      sc1 += fmaxf(acc1[j] + bb2, 0.f) * w3;
    }
    float st0 = sMeta[a0], hv0 = sMeta[32 + a0];
    float st1 = sMeta[A1], hv1 = sMeta[32 + A1];
    float bon0 = (hv0 > 0.5f) ? (tp0 * st0 + tp1 * (1.f - st0)) : tp3 * 2.f;
    float bon1 = (hv1 > 0.5f) ? (tp0 * st1 + tp1 * (1.f - st1)) : tp3 * 2.f;
    out[(size_t)(b0 + r) * 30 + a0] = sc0 + bon0;
    if (v1) out[(size_t)(b0 + r) * 30 + a1] = sc1 + bon1;
  }
}

// ---------------------------------------------------------------------------
extern "C" void kernel_launch(void* const* d_in, const int* in_sizes, int n_in,
                              void* d_out, int out_size, void* d_ws, size_t ws_size,
                              hipStream_t stream) {
  (void)in_sizes; (void)n_in; (void)out_size; (void)d_ws; (void)ws_size;
  const int* hand_cards = (const int*)d_in[0];
  const int* enemy_card = (const int*)d_in[1];
  const int* hand_size = (const int*)d_in[2];
  const float* game_state = (const float*)d_in[3];
  const float* discard = (const float*)d_in[4];
  const int* acards = (const int*)d_in[5];
  // d_in[6] = num_valid_actions (unused scalar)
  const float* val_emb = (const float*)d_in[7];
  const float* suit_emb = (const float*)d_in[8];
  const float* type_emb = (const float*)d_in[9];
  const float* ce_w1 = (const float*)d_in[10], * ce_b1 = (const float*)d_in[11];
  const float* ce_w2 = (const float*)d_in[12], * ce_b2 = (const float*)d_in[13];
  // d_in[14..21] = ha_* (hand self-attention) -- provably dead code, unused
  const float* he_wv = (const float*)d_in[26], * he_bv = (const float*)d_in[27];
  const float* he_wo = (const float*)d_in[28], * he_bo = (const float*)d_in[29];
  const float* se_w1 = (const float*)d_in[30], * se_b1 = (const float*)d_in[31];
  const float* se_w2 = (const float*)d_in[32], * se_b2 = (const float*)d_in[33];
  const float* atc_w1 = (const float*)d_in[34], * atc_b1 = (const float*)d_in[35];
  const float* atc_w2 = (const float*)d_in[36], * atc_b2 = (const float*)d_in[37];
  const float* as_w1 = (const float*)d_in[38], * as_b1 = (const float*)d_in[39];
  const float* as_w2 = (const float*)d_in[40], * as_b2 = (const float*)d_in[41];
  const float* as_w3 = (const float*)d_in[42], * as_b3 = (const float*)d_in[43];
  const float* cx_w1 = (const float*)d_in[44], * cx_b1 = (const float*)d_in[45];
  const float* cx_w2 = (const float*)d_in[46], * cx_b2 = (const float*)d_in[47];
  const float* cx_w3 = (const float*)d_in[48], * cx_b3 = (const float*)d_in[49];
  float* out = (float*)d_out;

  hipLaunchKernelGGL(policy_fused, dim3(16384 / MT), dim3(256), 0, stream,
                     hand_cards, enemy_card, hand_size, game_state, discard, acards,
                     val_emb, suit_emb, type_emb,
                     ce_w1, ce_b1, ce_w2, ce_b2,
                     he_wv, he_bv, he_wo, he_bo,
                     se_w1, se_b1, se_w2, se_b2,
                     atc_w1, atc_b1, atc_w2, atc_b2,
                     as_w1, as_b1, as_w2, as_b2, as_w3, as_b3,
                     cx_w1, cx_b1, cx_w2, cx_b2, cx_w3, cx_b3,
                     out);
}

// Round 5
// 324.823 us; speedup vs baseline: 1.0917x; 1.0917x over previous
//
#include <hip/hip_runtime.h>
#include <math.h>

#define MT 16        // batch rows per block -> grid 1024 = exactly 4 blocks/CU
#define XS 152       // sX row stride (even for float2; 152%32=24 -> rows on distinct banks)
#define BSB 132      // sB row stride (even; 132%32=4 -> rows on distinct banks)
#define QS 66        // sQa row stride (even; 66%32=2 -> 16 action rows on distinct banks)

// ---------------------------------------------------------------------------
// card encoding: ce = [val_emb[v], suit_emb[s]] + [type_emb[ct], 0...]
// ---------------------------------------------------------------------------
__device__ __forceinline__ void encode_card32(int c,
                                              const float* __restrict__ val_emb,
                                              const float* __restrict__ suit_emb,
                                              const float* __restrict__ type_emb,
                                              float* e) {
  bool inv = (c == 0) || (c == 53);
  int v = inv ? 0 : ((c - 1) % 13 + 1);
  int s = inv ? 0 : ((c - 1) / 13 + 1);
  int ct = (v == 11) ? 1 : (v == 12) ? 2 : (v == 13) ? 3 : 0;
#pragma unroll
  for (int i = 0; i < 16; ++i) e[i] = val_emb[v * 16 + i];
#pragma unroll
  for (int i = 0; i < 16; ++i) e[16 + i] = suit_emb[s * 16 + i];
#pragma unroll
  for (int i = 0; i < 8; ++i) e[i] += type_emb[ct * 8 + i];
}

// ---------------------------------------------------------------------------
// 128-wide layer, LDS-staged weights in 16-row tiles (8 KB), (m,n)=(4,2) tiling:
// thread = (rg = tid&3 -> rows rg+4i, cg = tid>>2 -> cols cg*2, cg*2+1).
// Weight read: one ds_read_b64/kk covering all 32 banks exactly once (no conflicts).
// Act reads: float2 (2 kk), 4 distinct rows/instr on distinct banks.
// ---------------------------------------------------------------------------
template <int K, bool RELU>
__device__ __forceinline__ void layer128_lds(
    const float* __restrict__ actIn, int is, float* __restrict__ actOut, int os,
    const float* __restrict__ W, const float* __restrict__ bias,
    float* __restrict__ wbuf) {
  const int tid = threadIdx.x;
  const int rg = tid & 3;
  const int c0 = (tid >> 2) * 2;
  float2 acc0, acc1, acc2, acc3;
  {
    float2 bv = *(const float2*)&bias[c0];
    acc0 = bv; acc1 = bv; acc2 = bv; acc3 = bv;
  }
  constexpr int FT = K / 16;
  constexpr int TAIL = K - FT * 16;
#pragma unroll 1
  for (int t = 0; t < FT; ++t) {
    const int k0 = t * 16;
    __syncthreads();  // previous wbuf tile fully consumed
#pragma unroll
    for (int p = 0; p < 2; ++p) {
      int idx = tid * 4 + p * 1024;
      *(float4*)&wbuf[idx] = *(const float4*)&W[(size_t)k0 * 128 + idx];
    }
    __syncthreads();
#pragma unroll
    for (int kk = 0; kk < 16; kk += 2) {
      float2 w0 = *(const float2*)&wbuf[kk * 128 + c0];
      float2 w1 = *(const float2*)&wbuf[(kk + 1) * 128 + c0];
      float2 a0 = *(const float2*)&actIn[(rg + 0) * is + k0 + kk];
      float2 a1 = *(const float2*)&actIn[(rg + 4) * is + k0 + kk];
      float2 a2 = *(const float2*)&actIn[(rg + 8) * is + k0 + kk];
      float2 a3 = *(const float2*)&actIn[(rg + 12) * is + k0 + kk];
      acc0.x += a0.x * w0.x + a0.y * w1.x;  acc0.y += a0.x * w0.y + a0.y * w1.y;
      acc1.x += a1.x * w0.x + a1.y * w1.x;  acc1.y += a1.x * w0.y + a1.y * w1.y;
      acc2.x += a2.x * w0.x + a2.y * w1.x;  acc2.y += a2.x * w0.y + a2.y * w1.y;
      acc3.x += a3.x * w0.x + a3.y * w1.x;  acc3.y += a3.x * w0.y + a3.y * w1.y;
    }
  }
  if constexpr (TAIL > 0) {
    const int k0 = FT * 16;
    __syncthreads();
    for (int idx = tid * 4; idx < TAIL * 128; idx += 1024)
      *(float4*)&wbuf[idx] = *(const float4*)&W[(size_t)k0 * 128 + idx];
    __syncthreads();
#pragma unroll
    for (int kk = 0; kk < TAIL; kk += 2) {
      float2 w0 = *(const float2*)&wbuf[kk * 128 + c0];
      float2 w1 = *(const float2*)&wbuf[(kk + 1) * 128 + c0];
      float2 a0 = *(const float2*)&actIn[(rg + 0) * is + k0 + kk];
      float2 a1 = *(const float2*)&actIn[(rg + 4) * is + k0 + kk];
      float2 a2 = *(const float2*)&actIn[(rg + 8) * is + k0 + kk];
      float2 a3 = *(const float2*)&actIn[(rg + 12) * is + k0 + kk];
      acc0.x += a0.x * w0.x + a0.y * w1.x;  acc0.y += a0.x * w0.y + a0.y * w1.y;
      acc1.x += a1.x * w0.x + a1.y * w1.x;  acc1.y += a1.x * w0.y + a1.y * w1.y;
      acc2.x += a2.x * w0.x + a2.y * w1.x;  acc2.y += a2.x * w0.y + a2.y * w1.y;
      acc3.x += a3.x * w0.x + a3.y * w1.x;  acc3.y += a3.x * w0.y + a3.y * w1.y;
    }
  }
  if (RELU) {
    acc0.x = fmaxf(acc0.x, 0.f); acc0.y = fmaxf(acc0.y, 0.f);
    acc1.x = fmaxf(acc1.x, 0.f); acc1.y = fmaxf(acc1.y, 0.f);
    acc2.x = fmaxf(acc2.x, 0.f); acc2.y = fmaxf(acc2.y, 0.f);
    acc3.x = fmaxf(acc3.x, 0.f); acc3.y = fmaxf(acc3.y, 0.f);
  }
  *(float2*)&actOut[(rg + 0) * os + c0] = acc0;
  *(float2*)&actOut[(rg + 4) * os + c0] = acc1;
  *(float2*)&actOut[(rg + 8) * os + c0] = acc2;
  *(float2*)&actOut[(rg + 12) * os + c0] = acc3;
}

// ---------------------------------------------------------------------------
// Dual 64-wide layer: cols [0:64) = t1 = relu(ctx@atc_w1+b), [64:128) = P = ctx@as_w1[:128].
// Same (4,2) structure; wbuf row = [Wt row | Wp row].
// ---------------------------------------------------------------------------
__device__ __forceinline__ void layer_dual64(
    const float* __restrict__ actIn, int is, float* __restrict__ actOut, int os,
    const float* __restrict__ Wt, const float* __restrict__ bt,
    const float* __restrict__ Wp, float* __restrict__ wbuf) {
  const int tid = threadIdx.x;
  const int rg = tid & 3;
  const int c0 = (tid >> 2) * 2;
  const bool isT = (c0 < 64);
  float2 acc0, acc1, acc2, acc3;
  {
    float2 bv = isT ? *(const float2*)&bt[c0] : make_float2(0.f, 0.f);
    acc0 = bv; acc1 = bv; acc2 = bv; acc3 = bv;
  }
#pragma unroll 1
  for (int t = 0; t < 8; ++t) {
    const int k0 = t * 16;
    __syncthreads();
#pragma unroll
    for (int p = 0; p < 2; ++p) {
      int idx = tid * 4 + p * 1024;
      int row = idx >> 7, c = idx & 127;
      const float* src = (c < 64) ? &Wt[(size_t)(k0 + row) * 64 + c]
                                  : &Wp[(size_t)(k0 + row) * 64 + (c - 64)];
      *(float4*)&wbuf[idx] = *(const float4*)src;
    }
    __syncthreads();
#pragma unroll
    for (int kk = 0; kk < 16; kk += 2) {
      float2 w0 = *(const float2*)&wbuf[kk * 128 + c0];
      float2 w1 = *(const float2*)&wbuf[(kk + 1) * 128 + c0];
      float2 a0 = *(const float2*)&actIn[(rg + 0) * is + k0 + kk];
      float2 a1 = *(const float2*)&actIn[(rg + 4) * is + k0 + kk];
      float2 a2 = *(const float2*)&actIn[(rg + 8) * is + k0 + kk];
      float2 a3 = *(const float2*)&actIn[(rg + 12) * is + k0 + kk];
      acc0.x += a0.x * w0.x + a0.y * w1.x;  acc0.y += a0.x * w0.y + a0.y * w1.y;
      acc1.x += a1.x * w0.x + a1.y * w1.x;  acc1.y += a1.x * w0.y + a1.y * w1.y;
      acc2.x += a2.x * w0.x + a2.y * w1.x;  acc2.y += a2.x * w0.y + a2.y * w1.y;
      acc3.x += a3.x * w0.x + a3.y * w1.x;  acc3.y += a3.x * w0.y + a3.y * w1.y;
    }
  }
  if (isT) {
    acc0.x = fmaxf(acc0.x, 0.f); acc0.y = fmaxf(acc0.y, 0.f);
    acc1.x = fmaxf(acc1.x, 0.f); acc1.y = fmaxf(acc1.y, 0.f);
    acc2.x = fmaxf(acc2.x, 0.f); acc2.y = fmaxf(acc2.y, 0.f);
    acc3.x = fmaxf(acc3.x, 0.f); acc3.y = fmaxf(acc3.y, 0.f);
  }
  *(float2*)&actOut[(rg + 0) * os + c0] = acc0;
  *(float2*)&actOut[(rg + 4) * os + c0] = acc1;
  *(float2*)&actOut[(rg + 8) * os + c0] = acc2;
  *(float2*)&actOut[(rg + 12) * os + c0] = acc3;
}

// ---------------------------------------------------------------------------
// Fused kernel. 16 rows/block, 256 threads, grid 1024. LDS ~35.3 KB -> 4 blk/CU
// (LDS is the occupancy limiter; NO min-waves launch bound — R4 showed
//  __launch_bounds__(256,4) clamps VGPR to 64 and spills P9's accumulators,
//  costing ~180 MB of scratch HBM traffic).
//   sX[r]: [0:32) hand_ctx | [32:64) enemy | [64:96) strat_ctx | [96:150) discard
//          later: GEMM ping buffer; finally [0:64) t1, [64:128) P
//   sB[r]: [0:20) strat_in | [20:84) t64 | [84:116) V ; later GEMM pong buffer
//   wbuf : action scratch, then 16-row weight tiles, finally as_w2 (64x32)
//   sQa[30][66], sMeta: strength/hasv/w3/b2
// ---------------------------------------------------------------------------
__global__ __launch_bounds__(256) void policy_fused(
    const int* __restrict__ hand_cards, const int* __restrict__ enemy_card,
    const int* __restrict__ hand_size, const float* __restrict__ game_state,
    const float* __restrict__ discard, const int* __restrict__ acards,
    const float* __restrict__ val_emb, const float* __restrict__ suit_emb,
    const float* __restrict__ type_emb,
    const float* __restrict__ ce_w1, const float* __restrict__ ce_b1,
    const float* __restrict__ ce_w2, const float* __restrict__ ce_b2,
    const float* __restrict__ he_wv, const float* __restrict__ he_bv,
    const float* __restrict__ he_wo, const float* __restrict__ he_bo,
    const float* __restrict__ se_w1, const float* __restrict__ se_b1,
    const float* __restrict__ se_w2, const float* __restrict__ se_b2,
    const float* __restrict__ atc_w1, const float* __restrict__ atc_b1,
    const float* __restrict__ atc_w2, const float* __restrict__ atc_b2,
    const float* __restrict__ as_w1, const float* __restrict__ as_b1,
    const float* __restrict__ as_w2, const float* __restrict__ as_b2,
    const float* __restrict__ as_w3, const float* __restrict__ as_b3,
    const float* __restrict__ cx_w1, const float* __restrict__ cx_b1,
    const float* __restrict__ cx_w2, const float* __restrict__ cx_b2,
    const float* __restrict__ cx_w3, const float* __restrict__ cx_b3,
    float* __restrict__ out) {
  __shared__ float sX[MT * XS];      // 9728 B
  __shared__ float sB[MT * BSB];     // 8448 B
  __shared__ float wbuf[2048];       // 8192 B
  __shared__ float sQa[30 * QS];     // 7920 B
  __shared__ float sMeta[128];       // 512 B
  __shared__ float sTp[MT * 4];
  __shared__ float sLen[MT];

  const int tid = threadIdx.x;
  const int b0 = blockIdx.x * MT;

  // ---------------- P0: global gathers + per-row features + action features --
  for (int idx = tid; idx < MT * 54; idx += 256) {
    int r = idx / 54, k = idx - r * 54;
    sX[r * XS + 96 + k] = discard[(size_t)b0 * 54 + idx];
  }
  for (int idx = tid; idx < MT * 10; idx += 256) {
    int r = idx / 10, k = idx - r * 10;
    sB[r * BSB + k] = game_state[(size_t)b0 * 10 + idx];
  }
  if (tid < MT) {
    const int b = b0 + tid;
    const float hsz = (float)hand_size[b];
    sLen[tid] = 8.0f / fmaxf(hsz, 1.0f);
    int aces = 0, faces = 0, low = 0, c1 = 0, c2 = 0, c3 = 0, c4 = 0;
#pragma unroll
    for (int i = 0; i < 8; ++i) {
      int c = hand_cards[b * 8 + i];
      int v = (c == 0) ? 0 : ((c - 1) % 13 + 1);
      int s = (c == 0) ? 0 : ((c - 1) / 13 + 1);
      aces += (v == 1);
      faces += (v >= 11 && v <= 13);
      low += (v >= 2 && v <= 6);
      c1 += (s == 1); c2 += (s == 2); c3 += (s == 3); c4 += (s == 4);
    }
    float sdiv = (float)((c1 > 0) + (c2 > 0) + (c3 > 0) + (c4 > 0)) * 0.25f;
    float hvr = (float)faces / (hsz + 1e-8f);
    float* si = &sB[tid * BSB];
    si[10] = hsz; si[11] = (float)aces; si[12] = (float)faces;
    si[13] = (float)low; si[14] = (float)c1; si[15] = (float)c2;
    si[16] = (float)c3; si[17] = (float)c4; si[18] = hvr; si[19] = sdiv;
    float e[32];
    encode_card32(enemy_card[b], val_emb, suit_emb, type_emb, e);
#pragma unroll
    for (int i = 0; i < 32; ++i) sX[tid * XS + 32 + i] = e[i];
  }
  if (tid < 30) {  // action features -> wbuf scratch + sMeta
    int c[4];
#pragma unroll
    for (int i = 0; i < 4; ++i) c[i] = acards[tid * 4 + i];
    bool mask[4]; int vals[4], suits[4]; int csize = 0; bool hasv = false;
#pragma unroll
    for (int i = 0; i < 4; ++i) {
      mask[i] = (c[i] != 0);
      if (mask[i]) { csize++; hasv = true; }
      vals[i] = mask[i] ? ((c[i] - 1) % 13 + 1) : 0;
      suits[i] = mask[i] ? ((c[i] - 1) / 13 + 1) : 0;
    }
    int fvv = mask[0] ? vals[0] : mask[1] ? vals[1] : mask[2] ? vals[2]
              : mask[3] ? vals[3] : vals[0];
    bool same = true;
#pragma unroll
    for (int i = 0; i < 4; ++i) if (mask[i] && vals[i] != fvv) same = false;
    float total = 0.f;
#pragma unroll
    for (int i = 0; i < 4; ++i) {
      if (mask[i]) {
        int v = vals[i];
        total += (v == 1) ? 1.f : (v == 11) ? 10.f : (v == 12) ? 15.f
                 : (v == 13) ? 20.f : (float)v;
      }
    }
    float uniq = 0.f;
#pragma unroll
    for (int s = 1; s <= 4; ++s) {
      bool any = false;
#pragma unroll
      for (int i = 0; i < 4; ++i) if (suits[i] == s) any = true;
      uniq += any ? 1.f : 0.f;
    }
    bool ace = false;
#pragma unroll
    for (int i = 0; i < 4; ++i) if (mask[i] && vals[i] == 1) ace = true;
    float f_same = same ? 1.f : 0.f, f_ace = ace ? 1.f : 0.f;
    float valid = (((float)csize <= 4.f) && (f_same > 0.f || f_ace > 0.f)) ? 1.f : 0.f;
    float feats[6] = {(float)csize, f_same, total, uniq, f_ace, valid};
    if (!hasv) { for (int i = 0; i < 6; ++i) feats[i] = 0.f; }
    float emb[32];
#pragma unroll
    for (int i = 0; i < 32; ++i) emb[i] = 0.f;
    float cnt = 0.f;
#pragma unroll
    for (int i = 0; i < 4; ++i) {
      float e[32];
      encode_card32(c[i], val_emb, suit_emb, type_emb, e);
      if (mask[i]) {
#pragma unroll
        for (int j = 0; j < 32; ++j) emb[j] += e[j];
        cnt += 1.f;
      }
    }
    float invc = 1.f / fmaxf(cnt, 1.f);
#pragma unroll
    for (int j = 0; j < 32; ++j)
      wbuf[tid * 32 + j] = hasv ? emb[j] * invc : 0.f;     // act_emb scratch
    float t32[32];
#pragma unroll
    for (int j = 0; j < 32; ++j) {
      float acc = ce_b1[j];
#pragma unroll
      for (int k = 0; k < 6; ++k) acc += feats[k] * ce_w1[k * 32 + j];
      t32[j] = fmaxf(acc, 0.f);
    }
#pragma unroll
    for (int j = 0; j < 16; ++j) {
      float acc = ce_b2[j];
#pragma unroll
      for (int k = 0; k < 32; ++k) acc += t32[k] * ce_w2[k * 16 + j];
      wbuf[960 + tid * 16 + j] = acc;                      // combo scratch
    }
    sMeta[tid] = feats[2] * 0.05f;       // strength
    sMeta[32 + tid] = hasv ? 1.f : 0.f;  // has_valid
  }
  if (tid < 32) {
    sMeta[64 + tid] = as_w3[tid];
    sMeta[96 + tid] = as_b2[tid];
  }
  __syncthreads();

  // ---------------- P1: Qa (wbuf scratch -> sQa); se L1 ---------------------
  for (int idx = tid; idx < 1920; idx += 256) {
    int a = idx >> 6, j = idx & 63;
    float acc = as_b1[j];
#pragma unroll
    for (int k = 0; k < 32; ++k) acc += wbuf[a * 32 + k] * as_w1[(128 + k) * 64 + j];
#pragma unroll
    for (int k = 0; k < 16; ++k) acc += wbuf[960 + a * 16 + k] * as_w1[(160 + k) * 64 + j];
    sQa[a * QS + j] = acc;
  }
  {
    const int r = tid >> 4, j0 = (tid & 15) * 4;
    float acc[4];
#pragma unroll
    for (int j = 0; j < 4; ++j) acc[j] = se_b1[j0 + j];
    for (int k = 0; k < 20; ++k) {
      float a = sB[r * BSB + k];
#pragma unroll
      for (int j = 0; j < 4; ++j) acc[j] += a * se_w1[k * 64 + j0 + j];
    }
#pragma unroll
    for (int j = 0; j < 4; ++j) sB[r * BSB + 20 + j0 + j] = fmaxf(acc[j], 0.f);
  }
  __syncthreads();

  // ---------------- P2: se L2 64->32 -> sX[64:96) ; V = enemy@wv -> sB[84:116)
  {
    const int r = tid >> 4, j0 = (tid & 15) * 2;
    float acc[2] = {se_b2[j0], se_b2[j0 + 1]};
    for (int k = 0; k < 64; ++k) {
      float a = sB[r * BSB + 20 + k];
      acc[0] += a * se_w2[k * 32 + j0];
      acc[1] += a * se_w2[k * 32 + j0 + 1];
    }
    sX[r * XS + 64 + j0] = acc[0];
    sX[r * XS + 64 + j0 + 1] = acc[1];
    float vacc[2] = {he_bv[j0], he_bv[j0 + 1]};
    for (int k = 0; k < 32; ++k) {
      float a = sX[r * XS + 32 + k];
      vacc[0] += a * he_wv[k * 32 + j0];
      vacc[1] += a * he_wv[k * 32 + j0 + 1];
    }
    sB[r * BSB + 84 + j0] = vacc[0];
    sB[r * BSB + 84 + j0 + 1] = vacc[1];
  }
  __syncthreads();

  // ---------------- P3: hand_ctx = (V@wo + bo) * 8/len -> sX[0:32) ----------
  {
    const int r = tid >> 4, j0 = (tid & 15) * 2;
    float acc[2] = {he_bo[j0], he_bo[j0 + 1]};
    for (int k = 0; k < 32; ++k) {
      float a = sB[r * BSB + 84 + k];
      acc[0] += a * he_wo[k * 32 + j0];
      acc[1] += a * he_wo[k * 32 + j0 + 1];
    }
    float scale = sLen[r];
    sX[r * XS + j0] = scale * acc[0];
    sX[r * XS + j0 + 1] = scale * acc[1];
  }
  // no barrier needed: each layer's leading stage-barrier orders these writes

  // ---------------- P4..P6: context MLP chain (LDS-staged weights) ----------
  layer128_lds<150, true>(sX, XS, sB, BSB, cx_w1, cx_b1, wbuf);
  layer128_lds<128, true>(sB, BSB, sX, XS, cx_w2, cx_b2, wbuf);
  layer128_lds<128, false>(sX, XS, sB, BSB, cx_w3, cx_b3, wbuf);

  // ---------------- P7: t1 | P from ctx (dual staged layer) -----------------
  layer_dual64(sB, BSB, sX, XS, atc_w1, atc_b1, as_w1, wbuf);
  __syncthreads();

  // overlay as_w2 into wbuf (made visible to P9 by P8's barriers)
#pragma unroll
  for (int p = 0; p < 2; ++p) {
    int idx = tid * 4 + p * 1024;
    *(float4*)&wbuf[idx] = *(const float4*)&as_w2[idx];
  }

  // ---------------- P8: type logits + softmax -------------------------------
  if (tid < MT * 4) {
    const int r = tid >> 2, j = tid & 3;
    float acc = atc_b2[j];
    for (int k = 0; k < 64; ++k) acc += sX[r * XS + k] * atc_w2[k * 4 + j];
    sTp[r * 4 + j] = acc;
  }
  __syncthreads();
  if (tid < MT) {
    float l0 = sTp[tid * 4 + 0], l1 = sTp[tid * 4 + 1];
    float l2 = sTp[tid * 4 + 2], l3 = sTp[tid * 4 + 3];
    float m = fmaxf(fmaxf(l0, l1), fmaxf(l2, l3));
    float e0 = expf(l0 - m), e1 = expf(l1 - m), e2 = expf(l2 - m), e3 = expf(l3 - m);
    float inv = 1.f / (e0 + e1 + e2 + e3);
    sTp[tid * 4 + 0] = e0 * inv; sTp[tid * 4 + 1] = e1 * inv;
    sTp[tid * 4 + 2] = e2 * inv; sTp[tid * 4 + 3] = e3 * inv;
  }
  __syncthreads();

  // ---------------- P9: scoring (16 rows x 30 actions; w2 from wbuf) --------
  {
    const int r = tid >> 4, a0 = tid & 15;
    const int a1 = a0 + 16;
    const bool v1 = (a1 < 30);
    const int A1 = v1 ? a1 : 0;
    const float b3v = as_b3[0];
    const float tp0 = sTp[r * 4 + 0], tp1 = sTp[r * 4 + 1], tp3 = sTp[r * 4 + 3];
    const float* Prow = &sX[r * XS + 64];
    const float* qa0 = &sQa[a0 * QS];
    const float* qa1 = &sQa[A1 * QS];
    float acc0[32], acc1[32];
#pragma unroll
    for (int j = 0; j < 32; ++j) { acc0[j] = 0.f; acc1[j] = 0.f; }
#pragma unroll 2
    for (int k = 0; k < 64; k += 2) {
      float2 p  = *(const float2*)&Prow[k];
      float2 q0 = *(const float2*)&qa0[k];
      float2 q1 = *(const float2*)&qa1[k];
      float s0a = fmaxf(p.x + q0.x, 0.f), s0b = fmaxf(p.y + q0.y, 0.f);
      float s1a = fmaxf(p.x + q1.x, 0.f), s1b = fmaxf(p.y + q1.y, 0.f);
#pragma unroll
      for (int j = 0; j < 32; j += 4) {
        float4 wA = *(const float4*)&wbuf[k * 32 + j];
        float4 wB = *(const float4*)&wbuf[(k + 1) * 32 + j];
        acc0[j + 0] += s0a * wA.x + s0b * wB.x;
        acc0[j + 1] += s0a * wA.y + s0b * wB.y;
        acc0[j + 2] += s0a * wA.z + s0b * wB.z;
        acc0[j + 3] += s0a * wA.w + s0b * wB.w;
        acc1[j + 0] += s1a * wA.x + s1b * wB.x;
        acc1[j + 1] += s1a * wA.y + s1b * wB.y;
        acc1[j + 2] += s1a * wA.z + s1b * wB.z;
        acc1[j + 3] += s1a * wA.w + s1b * wB.w;
      }
    }
    float sc0 = b3v, sc1 = b3v;
#pragma unroll
    for (int j = 0; j < 32; ++j) {
      float w3 = sMeta[64 + j], bb2 = sMeta[96 + j];
      sc0 += fmaxf(acc0[j] + bb2, 0.f) * w3;
      sc1 += fmaxf(acc1[j] + bb2, 0.f) * w3;
    }
    float st0 = sMeta[a0], hv0 = sMeta[32 + a0];
    float st1 = sMeta[A1], hv1 = sMeta[32 + A1];
    float bon0 = (hv0 > 0.5f) ? (tp0 * st0 + tp1 * (1.f - st0)) : tp3 * 2.f;
    float bon1 = (hv1 > 0.5f) ? (tp0 * st1 + tp1 * (1.f - st1)) : tp3 * 2.f;
    out[(size_t)(b0 + r) * 30 + a0] = sc0 + bon0;
    if (v1) out[(size_t)(b0 + r) * 30 + a1] = sc1 + bon1;
  }
}

// ---------------------------------------------------------------------------
extern "C" void kernel_launch(void* const* d_in, const int* in_sizes, int n_in,
                              void* d_out, int out_size, void* d_ws, size_t ws_size,
                              hipStream_t stream) {
  (void)in_sizes; (void)n_in; (void)out_size; (void)d_ws; (void)ws_size;
  const int* hand_cards = (const int*)d_in[0];
  const int* enemy_card = (const int*)d_in[1];
  const int* hand_size = (const int*)d_in[2];
  const float* game_state = (const float*)d_in[3];
  const float* discard = (const float*)d_in[4];
  const int* acards = (const int*)d_in[5];
  // d_in[6] = num_valid_actions (unused scalar)
  const float* val_emb = (const float*)d_in[7];
  const float* suit_emb = (const float*)d_in[8];
  const float* type_emb = (const float*)d_in[9];
  const float* ce_w1 = (const float*)d_in[10], * ce_b1 = (const float*)d_in[11];
  const float* ce_w2 = (const float*)d_in[12], * ce_b2 = (const float*)d_in[13];
  // d_in[14..21] = ha_* (hand self-attention) -- provably dead code, unused
  const float* he_wv = (const float*)d_in[26], * he_bv = (const float*)d_in[27];
  const float* he_wo = (const float*)d_in[28], * he_bo = (const float*)d_in[29];
  const float* se_w1 = (const float*)d_in[30], * se_b1 = (const float*)d_in[31];
  const float* se_w2 = (const float*)d_in[32], * se_b2 = (const float*)d_in[33];
  const float* atc_w1 = (const float*)d_in[34], * atc_b1 = (const float*)d_in[35];
  const float* atc_w2 = (const float*)d_in[36], * atc_b2 = (const float*)d_in[37];
  const float* as_w1 = (const float*)d_in[38], * as_b1 = (const float*)d_in[39];
  const float* as_w2 = (const float*)d_in[40], * as_b2 = (const float*)d_in[41];
  const float* as_w3 = (const float*)d_in[42], * as_b3 = (const float*)d_in[43];
  const float* cx_w1 = (const float*)d_in[44], * cx_b1 = (const float*)d_in[45];
  const float* cx_w2 = (const float*)d_in[46], * cx_b2 = (const float*)d_in[47];
  const float* cx_w3 = (const float*)d_in[48], * cx_b3 = (const float*)d_in[49];
  float* out = (float*)d_out;

  hipLaunchKernelGGL(policy_fused, dim3(16384 / MT), dim3(256), 0, stream,
                     hand_cards, enemy_card, hand_size, game_state, discard, acards,
                     val_emb, suit_emb, type_emb,
                     ce_w1, ce_b1, ce_w2, ce_b2,
                     he_wv, he_bv, he_wo, he_bo,
                     se_w1, se_b1, se_w2, se_b2,
                     atc_w1, atc_b1, atc_w2, atc_b2,
                     as_w1, as_b1, as_w2, as_b2, as_w3, as_b3,
                     cx_w1, cx_b1, cx_w2, cx_b2, cx_w3, cx_b3,
                     out);
}

// Round 6
// 267.519 us; speedup vs baseline: 1.3256x; 1.2142x over previous
//
#include <hip/hip_runtime.h>
#include <math.h>

// ---------------------------------------------------------------------------
// Structure (R6): wave = 64 batch rows (lane = row), cols split across waves.
// All weights are wave-uniform -> s_load (SMEM pipe) + v_fmac with SGPR
// operand: weight traffic leaves the LDS pipe entirely. Activations live in
// LDS TRANSPOSED: act[k][row], so reads are lane-consecutive b32 (conflict-
// free). MT=64 rows/block, 512 threads (8 waves x 16 cols), grid 256.
// LDS = bufA[128][64] + bufB[128][64] = 64 KB exactly. Qa/strength/hasv
// precomputed into d_ws by a 1-block kernel (read via uniform s_load).
// NO min-waves launch bound (R4 lesson: it forces spills).
// ---------------------------------------------------------------------------

__device__ __forceinline__ void encode_card32(int c,
                                              const float* __restrict__ val_emb,
                                              const float* __restrict__ suit_emb,
                                              const float* __restrict__ type_emb,
                                              float* e) {
  bool inv = (c == 0) || (c == 53);
  int v = inv ? 0 : ((c - 1) % 13 + 1);
  int s = inv ? 0 : ((c - 1) / 13 + 1);
  int ct = (v == 11) ? 1 : (v == 12) ? 2 : (v == 13) ? 3 : 0;
#pragma unroll
  for (int i = 0; i < 16; ++i) e[i] = val_emb[v * 16 + i];
#pragma unroll
  for (int i = 0; i < 16; ++i) e[16 + i] = suit_emb[s * 16 + i];
#pragma unroll
  for (int i = 0; i < 8; ++i) e[i] += type_emb[ct * 8 + i];
}

// ---------------------------------------------------------------------------
// Kernel 1: per-action precompute (A=30), 1 block x 64 threads. Writes ws:
//   ws[0..1919]     Qa[a][j] = act_emb@as_w1[128:160] + combo@as_w1[160:176] + as_b1
//   ws[1920..1949]  strength[a] = feats_total/20
//   ws[1950..1979]  has_valid[a] (0/1)
// ---------------------------------------------------------------------------
__global__ __launch_bounds__(64) void action_kernel(
    const int* __restrict__ acards,
    const float* __restrict__ val_emb, const float* __restrict__ suit_emb,
    const float* __restrict__ type_emb,
    const float* __restrict__ ce_w1, const float* __restrict__ ce_b1,
    const float* __restrict__ ce_w2, const float* __restrict__ ce_b2,
    const float* __restrict__ as_w1, const float* __restrict__ as_b1,
    float* __restrict__ ws) {
  __shared__ float sAct[30][32];
  __shared__ float sCombo[30][16];
  const int tid = threadIdx.x;

  if (tid < 30) {
    int c[4];
#pragma unroll
    for (int i = 0; i < 4; ++i) c[i] = acards[tid * 4 + i];
    bool mask[4]; int vals[4], suits[4]; int csize = 0; bool hasv = false;
#pragma unroll
    for (int i = 0; i < 4; ++i) {
      mask[i] = (c[i] != 0);
      if (mask[i]) { csize++; hasv = true; }
      vals[i] = mask[i] ? ((c[i] - 1) % 13 + 1) : 0;
      suits[i] = mask[i] ? ((c[i] - 1) / 13 + 1) : 0;
    }
    int fvv = mask[0] ? vals[0] : mask[1] ? vals[1] : mask[2] ? vals[2]
              : mask[3] ? vals[3] : vals[0];
    bool same = true;
#pragma unroll
    for (int i = 0; i < 4; ++i) if (mask[i] && vals[i] != fvv) same = false;
    float total = 0.f;
#pragma unroll
    for (int i = 0; i < 4; ++i) {
      if (mask[i]) {
        int v = vals[i];
        total += (v == 1) ? 1.f : (v == 11) ? 10.f : (v == 12) ? 15.f
                 : (v == 13) ? 20.f : (float)v;
      }
    }
    float uniq = 0.f;
#pragma unroll
    for (int s = 1; s <= 4; ++s) {
      bool any = false;
#pragma unroll
      for (int i = 0; i < 4; ++i) if (suits[i] == s) any = true;
      uniq += any ? 1.f : 0.f;
    }
    bool ace = false;
#pragma unroll
    for (int i = 0; i < 4; ++i) if (mask[i] && vals[i] == 1) ace = true;
    float f_same = same ? 1.f : 0.f, f_ace = ace ? 1.f : 0.f;
    float valid = (((float)csize <= 4.f) && (f_same > 0.f || f_ace > 0.f)) ? 1.f : 0.f;
    float feats[6] = {(float)csize, f_same, total, uniq, f_ace, valid};
    if (!hasv) { for (int i = 0; i < 6; ++i) feats[i] = 0.f; }
    float emb[32];
#pragma unroll
    for (int i = 0; i < 32; ++i) emb[i] = 0.f;
    float cnt = 0.f;
#pragma unroll
    for (int i = 0; i < 4; ++i) {
      float e[32];
      encode_card32(c[i], val_emb, suit_emb, type_emb, e);
      if (mask[i]) {
#pragma unroll
        for (int j = 0; j < 32; ++j) emb[j] += e[j];
        cnt += 1.f;
      }
    }
    float invc = 1.f / fmaxf(cnt, 1.f);
#pragma unroll
    for (int j = 0; j < 32; ++j) sAct[tid][j] = hasv ? emb[j] * invc : 0.f;
    float t32[32];
#pragma unroll
    for (int j = 0; j < 32; ++j) {
      float acc = ce_b1[j];
#pragma unroll
      for (int k = 0; k < 6; ++k) acc += feats[k] * ce_w1[k * 32 + j];
      t32[j] = fmaxf(acc, 0.f);
    }
#pragma unroll
    for (int j = 0; j < 16; ++j) {
      float acc = ce_b2[j];
#pragma unroll
      for (int k = 0; k < 32; ++k) acc += t32[k] * ce_w2[k * 16 + j];
      sCombo[tid][j] = acc;
    }
    ws[1920 + tid] = total * 0.05f;
    ws[1950 + tid] = hasv ? 1.f : 0.f;
  }
  __syncthreads();
  for (int idx = tid; idx < 1920; idx += 64) {
    int a = idx >> 6, j = idx & 63;
    float acc = as_b1[j];
#pragma unroll
    for (int k = 0; k < 32; ++k) acc += sAct[a][k] * as_w1[(128 + k) * 64 + j];
#pragma unroll
    for (int k = 0; k < 16; ++k) acc += sCombo[a][k] * as_w1[(160 + k) * 64 + j];
    ws[idx] = acc;
  }
}

// ---------------------------------------------------------------------------
// Transposed layer: in[k][64] (LDS) -> out rows [j0, j0+NJ) of outB (LDS).
// Weights W[K][ldw] read at wave-uniform addresses -> s_load + SGPR-operand FMA.
// ---------------------------------------------------------------------------
template <int K, int NJ, bool RELU, bool HASB>
__device__ __forceinline__ void layerT(
    const float* __restrict__ inB, float* __restrict__ outB,
    const float* __restrict__ W, int ldw, int j0,
    const float* __restrict__ bias, int r) {
  float acc[NJ];
#pragma unroll
  for (int j = 0; j < NJ; ++j) acc[j] = HASB ? bias[j0 + j] : 0.f;
#pragma unroll 4
  for (int k = 0; k < K; ++k) {
    float a = inB[k * 64 + r];
    const float* wr = W + (size_t)k * ldw + j0;
#pragma unroll
    for (int j = 0; j < NJ; ++j) acc[j] += a * wr[j];
  }
#pragma unroll
  for (int j = 0; j < NJ; ++j)
    outB[(j0 + j) * 64 + r] = RELU ? fmaxf(acc[j], 0.f) : acc[j];
}

// ---------------------------------------------------------------------------
// Main kernel. 64 rows/block, 512 threads (8 waves), grid 256.
// bufA rows: [0:32) hand_ctx | [32:64) enemy | [64:96) strat_ctx   (combined)
//            then L2 out (h2), then P7 out: t1 rows [0:64), P rows [64:128)
// bufB rows: [0:20) strat_in | [20:84) t64 | [84:116) V | 116 sLen
//            then L1 out (h1), then L3 out (ctx), then logits rows [0:4)
// ---------------------------------------------------------------------------
__global__ __launch_bounds__(512) void policy_main(
    const int* __restrict__ hand_cards, const int* __restrict__ enemy_card,
    const int* __restrict__ hand_size, const float* __restrict__ game_state,
    const float* __restrict__ discard,
    const float* __restrict__ val_emb, const float* __restrict__ suit_emb,
    const float* __restrict__ type_emb,
    const float* __restrict__ he_wv, const float* __restrict__ he_bv,
    const float* __restrict__ he_wo, const float* __restrict__ he_bo,
    const float* __restrict__ se_w1, const float* __restrict__ se_b1,
    const float* __restrict__ se_w2, const float* __restrict__ se_b2,
    const float* __restrict__ atc_w1, const float* __restrict__ atc_b1,
    const float* __restrict__ atc_w2, const float* __restrict__ atc_b2,
    const float* __restrict__ as_w1,
    const float* __restrict__ as_w2, const float* __restrict__ as_b2,
    const float* __restrict__ as_w3, const float* __restrict__ as_b3,
    const float* __restrict__ cx_w1, const float* __restrict__ cx_b1,
    const float* __restrict__ cx_w2, const float* __restrict__ cx_b2,
    const float* __restrict__ cx_w3, const float* __restrict__ cx_b3,
    const float* __restrict__ ws, float* __restrict__ out) {
  __shared__ float bufA[128 * 64];   // 32 KB
  __shared__ float bufB[128 * 64];   // 32 KB

  const int tid = threadIdx.x;
  const int r = tid & 63;                                   // lane = batch row
  const int wq = __builtin_amdgcn_readfirstlane(tid >> 6);  // wave id (uniform)
  const int b0 = blockIdx.x * 64;

  // ---------------- P0: staging + per-row features --------------------------
  for (int idx = tid; idx < 64 * 10; idx += 512) {          // game_state -> bufB[k][r]
    int rr = idx / 10, k = idx - rr * 10;
    bufB[k * 64 + rr] = game_state[(size_t)b0 * 10 + idx];
  }
  if (tid < 64) {                                           // wave 0: row features
    const int b = b0 + r;
    const float hsz = (float)hand_size[b];
    bufB[116 * 64 + r] = 8.0f / fmaxf(hsz, 1.0f);           // sLen
    int aces = 0, faces = 0, low = 0, c1 = 0, c2 = 0, c3 = 0, c4 = 0;
#pragma unroll
    for (int i = 0; i < 8; ++i) {
      int c = hand_cards[b * 8 + i];
      int v = (c == 0) ? 0 : ((c - 1) % 13 + 1);
      int s = (c == 0) ? 0 : ((c - 1) / 13 + 1);
      aces += (v == 1);
      faces += (v >= 11 && v <= 13);
      low += (v >= 2 && v <= 6);
      c1 += (s == 1); c2 += (s == 2); c3 += (s == 3); c4 += (s == 4);
    }
    float sdiv = (float)((c1 > 0) + (c2 > 0) + (c3 > 0) + (c4 > 0)) * 0.25f;
    float hvr = (float)faces / (hsz + 1e-8f);
    bufB[(10 + 0) * 64 + r] = hsz;        bufB[(10 + 1) * 64 + r] = (float)aces;
    bufB[(10 + 2) * 64 + r] = (float)faces; bufB[(10 + 3) * 64 + r] = (float)low;
    bufB[(10 + 4) * 64 + r] = (float)c1;  bufB[(10 + 5) * 64 + r] = (float)c2;
    bufB[(10 + 6) * 64 + r] = (float)c3;  bufB[(10 + 7) * 64 + r] = (float)c4;
    bufB[(10 + 8) * 64 + r] = hvr;        bufB[(10 + 9) * 64 + r] = sdiv;
    float e[32];
    encode_card32(enemy_card[b], val_emb, suit_emb, type_emb, e);
#pragma unroll
    for (int i = 0; i < 32; ++i) bufA[(32 + i) * 64 + r] = e[i];
  }
  __syncthreads();

  // ---------------- P1: se L1 20->64 relu: bufB[0:20) -> bufB[20:84) --------
  layerT<20, 8, true, true>(bufB, bufB + 20 * 64, se_w1, 64, wq * 8, se_b1, r);
  __syncthreads();

  // ---------------- P2: se L2 64->32 -> bufA rows[64:96);  V -> bufB[84:116)
  layerT<64, 4, false, true>(bufB + 20 * 64, bufA + 64 * 64, se_w2, 32, wq * 4, se_b2, r);
  layerT<32, 4, false, true>(bufA + 32 * 64, bufB + 84 * 64, he_wv, 32, wq * 4, he_bv, r);
  __syncthreads();

  // ---------------- P3: hand_ctx = (V@wo + bo) * 8/len -> bufA rows[0:32) ---
  {
    const int j0 = wq * 4;
    float acc[4];
#pragma unroll
    for (int j = 0; j < 4; ++j) acc[j] = he_bo[j0 + j];
#pragma unroll 4
    for (int k = 0; k < 32; ++k) {
      float a = bufB[(84 + k) * 64 + r];
      const float* wr = he_wo + (size_t)k * 32 + j0;
#pragma unroll
      for (int j = 0; j < 4; ++j) acc[j] += a * wr[j];
    }
    float scale = bufB[116 * 64 + r];
#pragma unroll
    for (int j = 0; j < 4; ++j) bufA[(j0 + j) * 64 + r] = scale * acc[j];
  }
  __syncthreads();

  // ---------------- L1: 150->128 relu (96 LDS rows + 54 discard from global)
  {
    const int j0 = wq * 16;
    float acc[16];
#pragma unroll
    for (int j = 0; j < 16; ++j) acc[j] = cx_b1[j0 + j];
#pragma unroll 4
    for (int k = 0; k < 96; ++k) {
      float a = bufA[k * 64 + r];
      const float* wr = cx_w1 + (size_t)k * 128 + j0;
#pragma unroll
      for (int j = 0; j < 16; ++j) acc[j] += a * wr[j];
    }
    const float* drow = discard + (size_t)(b0 + r) * 54;
#pragma unroll 2
    for (int k = 0; k < 54; ++k) {
      float a = drow[k];
      const float* wr = cx_w1 + (size_t)(96 + k) * 128 + j0;
#pragma unroll
      for (int j = 0; j < 16; ++j) acc[j] += a * wr[j];
    }
    __syncthreads();   // everyone done reading bufB scratch before h1 overwrite
#pragma unroll
    for (int j = 0; j < 16; ++j) bufB[(j0 + j) * 64 + r] = fmaxf(acc[j], 0.f);
  }
  __syncthreads();

  // ---------------- L2: 128->128 relu  (bufB -> bufA) -----------------------
  layerT<128, 16, true, true>(bufB, bufA, cx_w2, 128, wq * 16, cx_b2, r);
  __syncthreads();

  // ---------------- L3: 128->128 (ctx)  (bufA -> bufB) ----------------------
  layerT<128, 16, false, true>(bufA, bufB, cx_w3, 128, wq * 16, cx_b3, r);
  __syncthreads();

  // ---------------- P7: t1 (waves 0-3) | P (waves 4-7)  (bufB -> bufA) ------
  if (wq < 4) {
    layerT<128, 16, true, true>(bufB, bufA, atc_w1, 64, wq * 16, atc_b1, r);
  } else {
    layerT<128, 16, false, false>(bufB, bufA + 64 * 64, as_w1, 64, (wq - 4) * 16,
                                  nullptr, r);
  }
  __syncthreads();

  // ---------------- P8: 4 type logits (wave wq<4 computes logit wq) ---------
  if (wq < 4) {
    float acc = atc_b2[wq];
#pragma unroll 4
    for (int k = 0; k < 64; ++k) acc += bufA[k * 64 + r] * atc_w2[k * 4 + wq];
    bufB[wq * 64 + r] = acc;   // overwrites ctx rows 0-3 (consumed)
  }
  __syncthreads();

  // ---------------- P9: scoring. wave -> 3-4 actions; lane -> row -----------
  {
    float l0 = bufB[0 * 64 + r], l1 = bufB[1 * 64 + r];
    float l2 = bufB[2 * 64 + r], l3 = bufB[3 * 64 + r];
    float m = fmaxf(fmaxf(l0, l1), fmaxf(l2, l3));
    float e0 = expf(l0 - m), e1 = expf(l1 - m), e2 = expf(l2 - m), e3 = expf(l3 - m);
    float inv = 1.f / (e0 + e1 + e2 + e3);
    float tp0 = e0 * inv, tp1 = e1 * inv, tp3 = e3 * inv;

    const int abase = (wq < 6) ? wq * 4 : 24 + (wq - 6) * 3;
    const int acnt = (wq < 6) ? 4 : 3;
    const float b3v = as_b3[0];
    for (int i = 0; i < acnt; ++i) {
      const int a = abase + i;                 // wave-uniform
      const float* qa = ws + a * 64;           // uniform -> s_load
      float acc[32];
#pragma unroll
      for (int j = 0; j < 32; ++j) acc[j] = 0.f;
#pragma unroll 1
      for (int seg = 0; seg < 4; ++seg) {
        float p[16];
#pragma unroll
        for (int kk = 0; kk < 16; ++kk)
          p[kk] = bufA[(64 + seg * 16 + kk) * 64 + r];
#pragma unroll
        for (int kk = 0; kk < 16; ++kk) {
          float s = fmaxf(p[kk] + qa[seg * 16 + kk], 0.f);
          const float* w2r = as_w2 + (size_t)(seg * 16 + kk) * 32;
#pragma unroll
          for (int j = 0; j < 32; ++j) acc[j] += s * w2r[j];
        }
      }
      float sc = b3v;
#pragma unroll
      for (int j = 0; j < 32; ++j)
        sc += fmaxf(acc[j] + as_b2[j], 0.f) * as_w3[j];
      float st = ws[1920 + a], hv = ws[1950 + a];
      float bon = (hv > 0.5f) ? (tp0 * st + tp1 * (1.f - st)) : tp3 * 2.f;
      out[(size_t)(b0 + r) * 30 + a] = sc + bon;
    }
  }
}

// ---------------------------------------------------------------------------
extern "C" void kernel_launch(void* const* d_in, const int* in_sizes, int n_in,
                              void* d_out, int out_size, void* d_ws, size_t ws_size,
                              hipStream_t stream) {
  (void)in_sizes; (void)n_in; (void)out_size; (void)ws_size;
  const int* hand_cards = (const int*)d_in[0];
  const int* enemy_card = (const int*)d_in[1];
  const int* hand_size = (const int*)d_in[2];
  const float* game_state = (const float*)d_in[3];
  const float* discard = (const float*)d_in[4];
  const int* acards = (const int*)d_in[5];
  // d_in[6] = num_valid_actions (unused scalar)
  const float* val_emb = (const float*)d_in[7];
  const float* suit_emb = (const float*)d_in[8];
  const float* type_emb = (const float*)d_in[9];
  const float* ce_w1 = (const float*)d_in[10], * ce_b1 = (const float*)d_in[11];
  const float* ce_w2 = (const float*)d_in[12], * ce_b2 = (const float*)d_in[13];
  // d_in[14..21] = ha_* (hand self-attention) -- provably dead code, unused
  const float* he_wv = (const float*)d_in[26], * he_bv = (const float*)d_in[27];
  const float* he_wo = (const float*)d_in[28], * he_bo = (const float*)d_in[29];
  const float* se_w1 = (const float*)d_in[30], * se_b1 = (const float*)d_in[31];
  const float* se_w2 = (const float*)d_in[32], * se_b2 = (const float*)d_in[33];
  const float* atc_w1 = (const float*)d_in[34], * atc_b1 = (const float*)d_in[35];
  const float* atc_w2 = (const float*)d_in[36], * atc_b2 = (const float*)d_in[37];
  const float* as_w1 = (const float*)d_in[38], * as_b1 = (const float*)d_in[39];
  const float* as_w2 = (const float*)d_in[40], * as_b2 = (const float*)d_in[41];
  const float* as_w3 = (const float*)d_in[42], * as_b3 = (const float*)d_in[43];
  const float* cx_w1 = (const float*)d_in[44], * cx_b1 = (const float*)d_in[45];
  const float* cx_w2 = (const float*)d_in[46], * cx_b2 = (const float*)d_in[47];
  const float* cx_w3 = (const float*)d_in[48], * cx_b3 = (const float*)d_in[49];
  float* ws = (float*)d_ws;
  float* out = (float*)d_out;

  hipLaunchKernelGGL(action_kernel, dim3(1), dim3(64), 0, stream,
                     acards, val_emb, suit_emb, type_emb,
                     ce_w1, ce_b1, ce_w2, ce_b2, as_w1, as_b1, ws);
  hipLaunchKernelGGL(policy_main, dim3(256), dim3(512), 0, stream,
                     hand_cards, enemy_card, hand_size, game_state, discard,
                     val_emb, suit_emb, type_emb,
                     he_wv, he_bv, he_wo, he_bo,
                     se_w1, se_b1, se_w2, se_b2,
                     atc_w1, atc_b1, atc_w2, atc_b2,
                     as_w1, as_w2, as_b2, as_w3, as_b3,
                     cx_w1, cx_b1, cx_w2, cx_b2, cx_w3, cx_b3,
                     ws, out);
}

// Round 7
// 259.393 us; speedup vs baseline: 1.3671x; 1.0313x over previous
//
#include <hip/hip_runtime.h>
#include <math.h>

// ---------------------------------------------------------------------------
// R7 structure: wave = 64 batch rows (lane = row), cols split across 16 waves.
// Weights are wave-uniform -> s_load (SMEM/constant pipe) + v_fmac with SGPR
// operand: weight traffic is off both LDS and VALU paths. Activations live in
// LDS TRANSPOSED: act[k][row]; reads are lane-consecutive b32 (conflict-free).
// MT=64 rows/block, 1024 threads (16 waves), grid 256 -> 16 waves/CU
// (4/SIMD; R6 had only 2/SIMD and stalled at VALUBusy 31%).
// LDS = bufA[128][64] + bufB[128][64] = 64 KB. Qa/strength/hasv precomputed
// into d_ws by a 1-block kernel (uniform s_load in the main kernel).
// NO min-waves launch bound (R4: it clamps VGPR and forces spills); plain
// __launch_bounds__(1024) keeps VGPR <= 128 so all 16 waves are resident.
// ---------------------------------------------------------------------------

__device__ __forceinline__ void encode_card32(int c,
                                              const float* __restrict__ val_emb,
                                              const float* __restrict__ suit_emb,
                                              const float* __restrict__ type_emb,
                                              float* e) {
  bool inv = (c == 0) || (c == 53);
  int v = inv ? 0 : ((c - 1) % 13 + 1);
  int s = inv ? 0 : ((c - 1) / 13 + 1);
  int ct = (v == 11) ? 1 : (v == 12) ? 2 : (v == 13) ? 3 : 0;
#pragma unroll
  for (int i = 0; i < 16; ++i) e[i] = val_emb[v * 16 + i];
#pragma unroll
  for (int i = 0; i < 16; ++i) e[16 + i] = suit_emb[s * 16 + i];
#pragma unroll
  for (int i = 0; i < 8; ++i) e[i] += type_emb[ct * 8 + i];
}

// ---------------------------------------------------------------------------
// Kernel 1: per-action precompute (A=30), 1 block x 64 threads. Writes ws:
//   ws[0..1919]     Qa[a][j] = act_emb@as_w1[128:160] + combo@as_w1[160:176] + as_b1
//   ws[1920..1949]  strength[a] = total/20
//   ws[1950..1979]  has_valid[a] (0/1)
// ---------------------------------------------------------------------------
__global__ __launch_bounds__(64) void action_kernel(
    const int* __restrict__ acards,
    const float* __restrict__ val_emb, const float* __restrict__ suit_emb,
    const float* __restrict__ type_emb,
    const float* __restrict__ ce_w1, const float* __restrict__ ce_b1,
    const float* __restrict__ ce_w2, const float* __restrict__ ce_b2,
    const float* __restrict__ as_w1, const float* __restrict__ as_b1,
    float* __restrict__ ws) {
  __shared__ float sAct[30][32];
  __shared__ float sCombo[30][16];
  const int tid = threadIdx.x;

  if (tid < 30) {
    int c[4];
#pragma unroll
    for (int i = 0; i < 4; ++i) c[i] = acards[tid * 4 + i];
    bool mask[4]; int vals[4], suits[4]; int csize = 0; bool hasv = false;
#pragma unroll
    for (int i = 0; i < 4; ++i) {
      mask[i] = (c[i] != 0);
      if (mask[i]) { csize++; hasv = true; }
      vals[i] = mask[i] ? ((c[i] - 1) % 13 + 1) : 0;
      suits[i] = mask[i] ? ((c[i] - 1) / 13 + 1) : 0;
    }
    int fvv = mask[0] ? vals[0] : mask[1] ? vals[1] : mask[2] ? vals[2]
              : mask[3] ? vals[3] : vals[0];
    bool same = true;
#pragma unroll
    for (int i = 0; i < 4; ++i) if (mask[i] && vals[i] != fvv) same = false;
    float total = 0.f;
#pragma unroll
    for (int i = 0; i < 4; ++i) {
      if (mask[i]) {
        int v = vals[i];
        total += (v == 1) ? 1.f : (v == 11) ? 10.f : (v == 12) ? 15.f
                 : (v == 13) ? 20.f : (float)v;
      }
    }
    float uniq = 0.f;
#pragma unroll
    for (int s = 1; s <= 4; ++s) {
      bool any = false;
#pragma unroll
      for (int i = 0; i < 4; ++i) if (suits[i] == s) any = true;
      uniq += any ? 1.f : 0.f;
    }
    bool ace = false;
#pragma unroll
    for (int i = 0; i < 4; ++i) if (mask[i] && vals[i] == 1) ace = true;
    float f_same = same ? 1.f : 0.f, f_ace = ace ? 1.f : 0.f;
    float valid = (((float)csize <= 4.f) && (f_same > 0.f || f_ace > 0.f)) ? 1.f : 0.f;
    float feats[6] = {(float)csize, f_same, total, uniq, f_ace, valid};
    if (!hasv) { for (int i = 0; i < 6; ++i) feats[i] = 0.f; }
    float emb[32];
#pragma unroll
    for (int i = 0; i < 32; ++i) emb[i] = 0.f;
    float cnt = 0.f;
#pragma unroll
    for (int i = 0; i < 4; ++i) {
      float e[32];
      encode_card32(c[i], val_emb, suit_emb, type_emb, e);
      if (mask[i]) {
#pragma unroll
        for (int j = 0; j < 32; ++j) emb[j] += e[j];
        cnt += 1.f;
      }
    }
    float invc = 1.f / fmaxf(cnt, 1.f);
#pragma unroll
    for (int j = 0; j < 32; ++j) sAct[tid][j] = hasv ? emb[j] * invc : 0.f;
    float t32[32];
#pragma unroll
    for (int j = 0; j < 32; ++j) {
      float acc = ce_b1[j];
#pragma unroll
      for (int k = 0; k < 6; ++k) acc += feats[k] * ce_w1[k * 32 + j];
      t32[j] = fmaxf(acc, 0.f);
    }
#pragma unroll
    for (int j = 0; j < 16; ++j) {
      float acc = ce_b2[j];
#pragma unroll
      for (int k = 0; k < 32; ++k) acc += t32[k] * ce_w2[k * 16 + j];
      sCombo[tid][j] = acc;
    }
    ws[1920 + tid] = total * 0.05f;
    ws[1950 + tid] = hasv ? 1.f : 0.f;
  }
  __syncthreads();
  for (int idx = tid; idx < 1920; idx += 64) {
    int a = idx >> 6, j = idx & 63;
    float acc = as_b1[j];
#pragma unroll
    for (int k = 0; k < 32; ++k) acc += sAct[a][k] * as_w1[(128 + k) * 64 + j];
#pragma unroll
    for (int k = 0; k < 16; ++k) acc += sCombo[a][k] * as_w1[(160 + k) * 64 + j];
    ws[idx] = acc;
  }
}

// ---------------------------------------------------------------------------
// Transposed layer: in[k][64] (LDS) -> out rows [j0, j0+NJ) of outB (LDS).
// W[K][ldw] read at wave-uniform addresses -> s_load + SGPR-operand FMA.
// ---------------------------------------------------------------------------
template <int K, int NJ, bool RELU, bool HASB>
__device__ __forceinline__ void layerT(
    const float* __restrict__ inB, float* __restrict__ outB,
    const float* __restrict__ W, int ldw, int j0,
    const float* __restrict__ bias, int r) {
  float acc[NJ];
#pragma unroll
  for (int j = 0; j < NJ; ++j) acc[j] = HASB ? bias[j0 + j] : 0.f;
#pragma unroll 4
  for (int k = 0; k < K; ++k) {
    float a = inB[k * 64 + r];
    const float* wr = W + (size_t)k * ldw + j0;
#pragma unroll
    for (int j = 0; j < NJ; ++j) acc[j] += a * wr[j];
  }
#pragma unroll
  for (int j = 0; j < NJ; ++j)
    outB[(j0 + j) * 64 + r] = RELU ? fmaxf(acc[j], 0.f) : acc[j];
}

// ---------------------------------------------------------------------------
// Main kernel. 64 rows/block, 1024 threads (16 waves), grid 256.
// bufA rows: [0:32) hand_ctx | [32:64) enemy | [64:96) strat_ctx   (combined)
//            then L2 out (h2), then P7 out: t1 rows [0:64), P rows [64:128)
// bufB rows: [0:20) strat_in | [20:84) t64 | [84:116) V | 116 sLen
//            then L1 out (h1), then L3 out (ctx), then logits rows [0:4)
// ---------------------------------------------------------------------------
__global__ __launch_bounds__(1024) void policy_main(
    const int* __restrict__ hand_cards, const int* __restrict__ enemy_card,
    const int* __restrict__ hand_size, const float* __restrict__ game_state,
    const float* __restrict__ discard,
    const float* __restrict__ val_emb, const float* __restrict__ suit_emb,
    const float* __restrict__ type_emb,
    const float* __restrict__ he_wv, const float* __restrict__ he_bv,
    const float* __restrict__ he_wo, const float* __restrict__ he_bo,
    const float* __restrict__ se_w1, const float* __restrict__ se_b1,
    const float* __restrict__ se_w2, const float* __restrict__ se_b2,
    const float* __restrict__ atc_w1, const float* __restrict__ atc_b1,
    const float* __restrict__ atc_w2, const float* __restrict__ atc_b2,
    const float* __restrict__ as_w1,
    const float* __restrict__ as_w2, const float* __restrict__ as_b2,
    const float* __restrict__ as_w3, const float* __restrict__ as_b3,
    const float* __restrict__ cx_w1, const float* __restrict__ cx_b1,
    const float* __restrict__ cx_w2, const float* __restrict__ cx_b2,
    const float* __restrict__ cx_w3, const float* __restrict__ cx_b3,
    const float* __restrict__ ws, float* __restrict__ out) {
  __shared__ float bufA[128 * 64];   // 32 KB
  __shared__ float bufB[128 * 64];   // 32 KB

  const int tid = threadIdx.x;
  const int r = tid & 63;                                   // lane = batch row
  const int wq = __builtin_amdgcn_readfirstlane(tid >> 6);  // wave id (uniform)
  const int b0 = blockIdx.x * 64;

  // ---------------- P0: staging + per-row features --------------------------
  if (wq == 2) {                                            // game_state -> bufB[k][r]
    // 64 rows x 10 cols staged by one wave: lane = row, loop cols
#pragma unroll
    for (int k = 0; k < 10; ++k)
      bufB[k * 64 + r] = game_state[(size_t)(b0 + r) * 10 + k];
  }
  if (wq == 0) {                                            // hand features
    const int b = b0 + r;
    const float hsz = (float)hand_size[b];
    int aces = 0, faces = 0, low = 0, c1 = 0, c2 = 0, c3 = 0, c4 = 0;
#pragma unroll
    for (int i = 0; i < 8; ++i) {
      int c = hand_cards[b * 8 + i];
      int v = (c == 0) ? 0 : ((c - 1) % 13 + 1);
      int s = (c == 0) ? 0 : ((c - 1) / 13 + 1);
      aces += (v == 1);
      faces += (v >= 11 && v <= 13);
      low += (v >= 2 && v <= 6);
      c1 += (s == 1); c2 += (s == 2); c3 += (s == 3); c4 += (s == 4);
    }
    float sdiv = (float)((c1 > 0) + (c2 > 0) + (c3 > 0) + (c4 > 0)) * 0.25f;
    float hvr = (float)faces / (hsz + 1e-8f);
    bufB[(10 + 0) * 64 + r] = hsz;          bufB[(10 + 1) * 64 + r] = (float)aces;
    bufB[(10 + 2) * 64 + r] = (float)faces; bufB[(10 + 3) * 64 + r] = (float)low;
    bufB[(10 + 4) * 64 + r] = (float)c1;    bufB[(10 + 5) * 64 + r] = (float)c2;
    bufB[(10 + 6) * 64 + r] = (float)c3;    bufB[(10 + 7) * 64 + r] = (float)c4;
    bufB[(10 + 8) * 64 + r] = hvr;          bufB[(10 + 9) * 64 + r] = sdiv;
  }
  if (wq == 1) {                                            // enemy encode + sLen
    const int b = b0 + r;
    bufB[116 * 64 + r] = 8.0f / fmaxf((float)hand_size[b], 1.0f);
    float e[32];
    encode_card32(enemy_card[b], val_emb, suit_emb, type_emb, e);
#pragma unroll
    for (int i = 0; i < 32; ++i) bufA[(32 + i) * 64 + r] = e[i];
  }
  __syncthreads();

  // ---------------- P1: se L1 20->64 relu: bufB[0:20) -> bufB[20:84) --------
  layerT<20, 4, true, true>(bufB, bufB + 20 * 64, se_w1, 64, wq * 4, se_b1, r);
  __syncthreads();

  // ---------------- P2: se L2 64->32 -> bufA rows[64:96);  V -> bufB[84:116)
  layerT<64, 2, false, true>(bufB + 20 * 64, bufA + 64 * 64, se_w2, 32, wq * 2, se_b2, r);
  layerT<32, 2, false, true>(bufA + 32 * 64, bufB + 84 * 64, he_wv, 32, wq * 2, he_bv, r);
  __syncthreads();

  // ---------------- P3: hand_ctx = (V@wo + bo) * 8/len -> bufA rows[0:32) ---
  {
    const int j0 = wq * 2;
    float acc[2] = {he_bo[j0], he_bo[j0 + 1]};
#pragma unroll 4
    for (int k = 0; k < 32; ++k) {
      float a = bufB[(84 + k) * 64 + r];
      const float* wr = he_wo + (size_t)k * 32 + j0;
      acc[0] += a * wr[0];
      acc[1] += a * wr[1];
    }
    float scale = bufB[116 * 64 + r];
    bufA[(j0 + 0) * 64 + r] = scale * acc[0];
    bufA[(j0 + 1) * 64 + r] = scale * acc[1];
  }
  __syncthreads();

  // ---------------- L1: 150->128 relu (96 LDS rows + 54 discard from global)
  {
    const int j0 = wq * 8;
    float acc[8];
#pragma unroll
    for (int j = 0; j < 8; ++j) acc[j] = cx_b1[j0 + j];
#pragma unroll 4
    for (int k = 0; k < 96; ++k) {
      float a = bufA[k * 64 + r];
      const float* wr = cx_w1 + (size_t)k * 128 + j0;
#pragma unroll
      for (int j = 0; j < 8; ++j) acc[j] += a * wr[j];
    }
    const float* drow = discard + (size_t)(b0 + r) * 54;
#pragma unroll 2
    for (int k = 0; k < 54; ++k) {
      float a = drow[k];
      const float* wr = cx_w1 + (size_t)(96 + k) * 128 + j0;
#pragma unroll
      for (int j = 0; j < 8; ++j) acc[j] += a * wr[j];
    }
    __syncthreads();   // everyone done reading bufB scratch before h1 overwrite
#pragma unroll
    for (int j = 0; j < 8; ++j) bufB[(j0 + j) * 64 + r] = fmaxf(acc[j], 0.f);
  }
  __syncthreads();

  // ---------------- L2: 128->128 relu  (bufB -> bufA) -----------------------
  layerT<128, 8, true, true>(bufB, bufA, cx_w2, 128, wq * 8, cx_b2, r);
  __syncthreads();

  // ---------------- L3: 128->128 (ctx)  (bufA -> bufB) ----------------------
  layerT<128, 8, false, true>(bufA, bufB, cx_w3, 128, wq * 8, cx_b3, r);
  __syncthreads();

  // ---------------- P7: t1 (waves 0-7) | P (waves 8-15)  (bufB -> bufA) -----
  if (wq < 8) {
    layerT<128, 8, true, true>(bufB, bufA, atc_w1, 64, wq * 8, atc_b1, r);
  } else {
    layerT<128, 8, false, false>(bufB, bufA + 64 * 64, as_w1, 64, (wq - 8) * 8,
                                 nullptr, r);
  }
  __syncthreads();

  // ---------------- P8: 4 type logits (wave wq<4 computes logit wq) ---------
  if (wq < 4) {
    float acc = atc_b2[wq];
#pragma unroll 4
    for (int k = 0; k < 64; ++k) acc += bufA[k * 64 + r] * atc_w2[k * 4 + wq];
    bufB[wq * 64 + r] = acc;   // overwrites ctx rows 0-3 (consumed)
  }
  __syncthreads();

  // ---------------- P9: scoring. waves 0-14 -> 2 actions each; lane -> row --
  if (wq < 15) {
    float l0 = bufB[0 * 64 + r], l1 = bufB[1 * 64 + r];
    float l2 = bufB[2 * 64 + r], l3 = bufB[3 * 64 + r];
    float m = fmaxf(fmaxf(l0, l1), fmaxf(l2, l3));
    float e0 = expf(l0 - m), e1 = expf(l1 - m), e2 = expf(l2 - m), e3 = expf(l3 - m);
    float inv = 1.f / (e0 + e1 + e2 + e3);
    float tp0 = e0 * inv, tp1 = e1 * inv, tp3 = e3 * inv;

    const float b3v = as_b3[0];
#pragma unroll 1
    for (int i = 0; i < 2; ++i) {
      const int a = wq * 2 + i;                // wave-uniform
      const float* qa = ws + a * 64;           // uniform -> s_load
      float acc[32];
#pragma unroll
      for (int j = 0; j < 32; ++j) acc[j] = 0.f;
#pragma unroll 1
      for (int seg = 0; seg < 4; ++seg) {
        float p[16];
#pragma unroll
        for (int kk = 0; kk < 16; ++kk)
          p[kk] = bufA[(64 + seg * 16 + kk) * 64 + r];
#pragma unroll
        for (int kk = 0; kk < 16; ++kk) {
          float s = fmaxf(p[kk] + qa[seg * 16 + kk], 0.f);
          const float* w2r = as_w2 + (size_t)(seg * 16 + kk) * 32;
#pragma unroll
          for (int j = 0; j < 32; ++j) acc[j] += s * w2r[j];
        }
      }
      float sc = b3v;
#pragma unroll
      for (int j = 0; j < 32; ++j)
        sc += fmaxf(acc[j] + as_b2[j], 0.f) * as_w3[j];
      float st = ws[1920 + a], hv = ws[1950 + a];
      float bon = (hv > 0.5f) ? (tp0 * st + tp1 * (1.f - st)) : tp3 * 2.f;
      out[(size_t)(b0 + r) * 30 + a] = sc + bon;
    }
  }
}

// ---------------------------------------------------------------------------
extern "C" void kernel_launch(void* const* d_in, const int* in_sizes, int n_in,
                              void* d_out, int out_size, void* d_ws, size_t ws_size,
                              hipStream_t stream) {
  (void)in_sizes; (void)n_in; (void)out_size; (void)ws_size;
  const int* hand_cards = (const int*)d_in[0];
  const int* enemy_card = (const int*)d_in[1];
  const int* hand_size = (const int*)d_in[2];
  const float* game_state = (const float*)d_in[3];
  const float* discard = (const float*)d_in[4];
  const int* acards = (const int*)d_in[5];
  // d_in[6] = num_valid_actions (unused scalar)
  const float* val_emb = (const float*)d_in[7];
  const float* suit_emb = (const float*)d_in[8];
  const float* type_emb = (const float*)d_in[9];
  const float* ce_w1 = (const float*)d_in[10], * ce_b1 = (const float*)d_in[11];
  const float* ce_w2 = (const float*)d_in[12], * ce_b2 = (const float*)d_in[13];
  // d_in[14..21] = ha_* (hand self-attention) -- provably dead code, unused
  const float* he_wv = (const float*)d_in[26], * he_bv = (const float*)d_in[27];
  const float* he_wo = (const float*)d_in[28], * he_bo = (const float*)d_in[29];
  const float* se_w1 = (const float*)d_in[30], * se_b1 = (const float*)d_in[31];
  const float* se_w2 = (const float*)d_in[32], * se_b2 = (const float*)d_in[33];
  const float* atc_w1 = (const float*)d_in[34], * atc_b1 = (const float*)d_in[35];
  const float* atc_w2 = (const float*)d_in[36], * atc_b2 = (const float*)d_in[37];
  const float* as_w1 = (const float*)d_in[38], * as_b1 = (const float*)d_in[39];
  const float* as_w2 = (const float*)d_in[40], * as_b2 = (const float*)d_in[41];
  const float* as_w3 = (const float*)d_in[42], * as_b3 = (const float*)d_in[43];
  const float* cx_w1 = (const float*)d_in[44], * cx_b1 = (const float*)d_in[45];
  const float* cx_w2 = (const float*)d_in[46], * cx_b2 = (const float*)d_in[47];
  const float* cx_w3 = (const float*)d_in[48], * cx_b3 = (const float*)d_in[49];
  float* ws = (float*)d_ws;
  float* out = (float*)d_out;

  hipLaunchKernelGGL(action_kernel, dim3(1), dim3(64), 0, stream,
                     acards, val_emb, suit_emb, type_emb,
                     ce_w1, ce_b1, ce_w2, ce_b2, as_w1, as_b1, ws);
  hipLaunchKernelGGL(policy_main, dim3(256), dim3(1024), 0, stream,
                     hand_cards, enemy_card, hand_size, game_state, discard,
                     val_emb, suit_emb, type_emb,
                     he_wv, he_bv, he_wo, he_bo,
                     se_w1, se_b1, se_w2, se_b2,
                     atc_w1, atc_b1, atc_w2, atc_b2,
                     as_w1, as_w2, as_b2, as_w3, as_b3,
                     cx_w1, cx_b1, cx_w2, cx_b2, cx_w3, cx_b3,
                     ws, out);
}

// Round 8
// 244.125 us; speedup vs baseline: 1.4526x; 1.0625x over previous
//
#include <hip/hip_runtime.h>
#include <math.h>

// ---------------------------------------------------------------------------
// R8 structure: wave = 64 batch rows (lane = row), cols split across 16 waves,
// weights via wave-uniform s_load (SMEM pipe) + SGPR-operand FMA.
// NEW vs R7: activations for the big layers are QUAD-PACKED in LDS:
//   buf[(k>>2)*256 + r*4 + (k&3)]
// so one ds_read_b128 (lane addr r*16, conflict-free) yields 4 k-values ->
// 32 FMA per LDS read (R7 was 8:1 with ds_read_b32; the single per-CU LDS
// pipe was oversubscribed 1.45x). Layer outputs are 2 ds_write_b128 per wave.
// MT=64 rows/block, 1024 threads (16 waves), grid 256. LDS 64 KB.
// NO min-waves launch bound (R4: clamps VGPR -> spills).
// ---------------------------------------------------------------------------

#define QOFF(c, r) ((((c) >> 2) * 256) + ((r) * 4) + ((c) & 3))

__device__ __forceinline__ void encode_card32(int c,
                                              const float* __restrict__ val_emb,
                                              const float* __restrict__ suit_emb,
                                              const float* __restrict__ type_emb,
                                              float* e) {
  bool inv = (c == 0) || (c == 53);
  int v = inv ? 0 : ((c - 1) % 13 + 1);
  int s = inv ? 0 : ((c - 1) / 13 + 1);
  int ct = (v == 11) ? 1 : (v == 12) ? 2 : (v == 13) ? 3 : 0;
#pragma unroll
  for (int i = 0; i < 16; ++i) e[i] = val_emb[v * 16 + i];
#pragma unroll
  for (int i = 0; i < 16; ++i) e[16 + i] = suit_emb[s * 16 + i];
#pragma unroll
  for (int i = 0; i < 8; ++i) e[i] += type_emb[ct * 8 + i];
}

// ---------------------------------------------------------------------------
// Kernel 1: per-action precompute (A=30), 1 block x 64 threads. Writes ws:
//   ws[0..1919]     Qa[a][j];  ws[1920..1949] strength;  ws[1950..1979] has_valid
// ---------------------------------------------------------------------------
__global__ __launch_bounds__(64) void action_kernel(
    const int* __restrict__ acards,
    const float* __restrict__ val_emb, const float* __restrict__ suit_emb,
    const float* __restrict__ type_emb,
    const float* __restrict__ ce_w1, const float* __restrict__ ce_b1,
    const float* __restrict__ ce_w2, const float* __restrict__ ce_b2,
    const float* __restrict__ as_w1, const float* __restrict__ as_b1,
    float* __restrict__ ws) {
  __shared__ float sAct[30][32];
  __shared__ float sCombo[30][16];
  const int tid = threadIdx.x;

  if (tid < 30) {
    int c[4];
#pragma unroll
    for (int i = 0; i < 4; ++i) c[i] = acards[tid * 4 + i];
    bool mask[4]; int vals[4], suits[4]; int csize = 0; bool hasv = false;
#pragma unroll
    for (int i = 0; i < 4; ++i) {
      mask[i] = (c[i] != 0);
      if (mask[i]) { csize++; hasv = true; }
      vals[i] = mask[i] ? ((c[i] - 1) % 13 + 1) : 0;
      suits[i] = mask[i] ? ((c[i] - 1) / 13 + 1) : 0;
    }
    int fvv = mask[0] ? vals[0] : mask[1] ? vals[1] : mask[2] ? vals[2]
              : mask[3] ? vals[3] : vals[0];
    bool same = true;
#pragma unroll
    for (int i = 0; i < 4; ++i) if (mask[i] && vals[i] != fvv) same = false;
    float total = 0.f;
#pragma unroll
    for (int i = 0; i < 4; ++i) {
      if (mask[i]) {
        int v = vals[i];
        total += (v == 1) ? 1.f : (v == 11) ? 10.f : (v == 12) ? 15.f
                 : (v == 13) ? 20.f : (float)v;
      }
    }
    float uniq = 0.f;
#pragma unroll
    for (int s = 1; s <= 4; ++s) {
      bool any = false;
#pragma unroll
      for (int i = 0; i < 4; ++i) if (suits[i] == s) any = true;
      uniq += any ? 1.f : 0.f;
    }
    bool ace = false;
#pragma unroll
    for (int i = 0; i < 4; ++i) if (mask[i] && vals[i] == 1) ace = true;
    float f_same = same ? 1.f : 0.f, f_ace = ace ? 1.f : 0.f;
    float valid = (((float)csize <= 4.f) && (f_same > 0.f || f_ace > 0.f)) ? 1.f : 0.f;
    float feats[6] = {(float)csize, f_same, total, uniq, f_ace, valid};
    if (!hasv) { for (int i = 0; i < 6; ++i) feats[i] = 0.f; }
    float emb[32];
#pragma unroll
    for (int i = 0; i < 32; ++i) emb[i] = 0.f;
    float cnt = 0.f;
#pragma unroll
    for (int i = 0; i < 4; ++i) {
      float e[32];
      encode_card32(c[i], val_emb, suit_emb, type_emb, e);
      if (mask[i]) {
#pragma unroll
        for (int j = 0; j < 32; ++j) emb[j] += e[j];
        cnt += 1.f;
      }
    }
    float invc = 1.f / fmaxf(cnt, 1.f);
#pragma unroll
    for (int j = 0; j < 32; ++j) sAct[tid][j] = hasv ? emb[j] * invc : 0.f;
    float t32[32];
#pragma unroll
    for (int j = 0; j < 32; ++j) {
      float acc = ce_b1[j];
#pragma unroll
      for (int k = 0; k < 6; ++k) acc += feats[k] * ce_w1[k * 32 + j];
      t32[j] = fmaxf(acc, 0.f);
    }
#pragma unroll
    for (int j = 0; j < 16; ++j) {
      float acc = ce_b2[j];
#pragma unroll
      for (int k = 0; k < 32; ++k) acc += t32[k] * ce_w2[k * 16 + j];
      sCombo[tid][j] = acc;
    }
    ws[1920 + tid] = total * 0.05f;
    ws[1950 + tid] = hasv ? 1.f : 0.f;
  }
  __syncthreads();
  for (int idx = tid; idx < 1920; idx += 64) {
    int a = idx >> 6, j = idx & 63;
    float acc = as_b1[j];
#pragma unroll
    for (int k = 0; k < 32; ++k) acc += sAct[a][k] * as_w1[(128 + k) * 64 + j];
#pragma unroll
    for (int k = 0; k < 16; ++k) acc += sCombo[a][k] * as_w1[(160 + k) * 64 + j];
    ws[idx] = acc;
  }
}

// ---------------------------------------------------------------------------
// Unified layer: QIN = quad-packed input (ds_read_b128, 4 k per read),
// else simple [k][64]. QOUT = quad-packed output (b128 stores when NJ==8).
// W read wave-uniformly (s_load + SGPR-operand FMA).
// ---------------------------------------------------------------------------
template <int K, int NJ, bool RELU, bool HASB, bool QIN, bool QOUT>
__device__ __forceinline__ void layerU(
    const float* __restrict__ in, int inColBase, float* __restrict__ outB,
    int outColBase, const float* __restrict__ W, int ldw, int j0,
    const float* __restrict__ bias, int r) {
  float acc[NJ];
#pragma unroll
  for (int j = 0; j < NJ; ++j) acc[j] = HASB ? bias[j0 + j] : 0.f;
  if constexpr (QIN) {
    static_assert(K % 4 == 0, "quad input needs K%4==0");
    const int g0 = inColBase >> 2;
#pragma unroll 4
    for (int g = 0; g < K / 4; ++g) {
      float4 a = *(const float4*)&in[(g0 + g) * 256 + r * 4];
#pragma unroll
      for (int q = 0; q < 4; ++q) {
        float av = (q == 0) ? a.x : (q == 1) ? a.y : (q == 2) ? a.z : a.w;
        const float* wr = W + (size_t)(g * 4 + q) * ldw + j0;
#pragma unroll
        for (int j = 0; j < NJ; ++j) acc[j] += av * wr[j];
      }
    }
  } else {
#pragma unroll 4
    for (int k = 0; k < K; ++k) {
      float a = in[(inColBase + k) * 64 + r];
      const float* wr = W + (size_t)k * ldw + j0;
#pragma unroll
      for (int j = 0; j < NJ; ++j) acc[j] += a * wr[j];
    }
  }
#pragma unroll
  for (int j = 0; j < NJ; ++j) if (RELU) acc[j] = fmaxf(acc[j], 0.f);
  if constexpr (QOUT && NJ == 8) {
    // j0 is a multiple of 8 -> two aligned quad groups
    const int c0 = outColBase + j0;
    float4 o0 = make_float4(acc[0], acc[1], acc[2], acc[3]);
    float4 o1 = make_float4(acc[4], acc[5], acc[6], acc[7]);
    *(float4*)&outB[(c0 >> 2) * 256 + r * 4] = o0;
    *(float4*)&outB[((c0 >> 2) + 1) * 256 + r * 4] = o1;
  } else if constexpr (QOUT) {
#pragma unroll
    for (int j = 0; j < NJ; ++j) outB[QOFF(outColBase + j0 + j, r)] = acc[j];
  } else {
#pragma unroll
    for (int j = 0; j < NJ; ++j) outB[(outColBase + j0 + j) * 64 + r] = acc[j];
  }
}

// ---------------------------------------------------------------------------
// Main kernel. 64 rows/block, 1024 threads (16 waves), grid 256.
// bufA (quad): combined cols [0:32) hand_ctx | [32:64) enemy | [64:96) strat_ctx
//              -> later h2 (128) -> later t1 cols [0:64) | P cols [64:128)
// bufB: simple scratch rows [0:20) strat_in | [20:84) t64 | [84:116) V | 116 sLen
//       -> later quad h1 (128) -> quad ctx (128) -> logits rows [0:4) (simple)
// ---------------------------------------------------------------------------
__global__ __launch_bounds__(1024) void policy_main(
    const int* __restrict__ hand_cards, const int* __restrict__ enemy_card,
    const int* __restrict__ hand_size, const float* __restrict__ game_state,
    const float* __restrict__ discard,
    const float* __restrict__ val_emb, const float* __restrict__ suit_emb,
    const float* __restrict__ type_emb,
    const float* __restrict__ he_wv, const float* __restrict__ he_bv,
    const float* __restrict__ he_wo, const float* __restrict__ he_bo,
    const float* __restrict__ se_w1, const float* __restrict__ se_b1,
    const float* __restrict__ se_w2, const float* __restrict__ se_b2,
    const float* __restrict__ atc_w1, const float* __restrict__ atc_b1,
    const float* __restrict__ atc_w2, const float* __restrict__ atc_b2,
    const float* __restrict__ as_w1,
    const float* __restrict__ as_w2, const float* __restrict__ as_b2,
    const float* __restrict__ as_w3, const float* __restrict__ as_b3,
    const float* __restrict__ cx_w1, const float* __restrict__ cx_b1,
    const float* __restrict__ cx_w2, const float* __restrict__ cx_b2,
    const float* __restrict__ cx_w3, const float* __restrict__ cx_b3,
    const float* __restrict__ ws, float* __restrict__ out) {
  __shared__ float bufA[128 * 64];   // 32 KB (quad-packed)
  __shared__ float bufB[128 * 64];   // 32 KB (simple scratch, then quad)

  const int tid = threadIdx.x;
  const int r = tid & 63;                                   // lane = batch row
  const int wq = __builtin_amdgcn_readfirstlane(tid >> 6);  // wave id (uniform)
  const int b0 = blockIdx.x * 64;

  // ---------------- P0: staging + per-row features --------------------------
  if (wq == 2) {                                            // game_state rows 0..9
#pragma unroll
    for (int k = 0; k < 10; ++k)
      bufB[k * 64 + r] = game_state[(size_t)(b0 + r) * 10 + k];
  }
  if (wq == 0) {                                            // hand features rows 10..19
    const int b = b0 + r;
    const float hsz = (float)hand_size[b];
    int aces = 0, faces = 0, low = 0, c1 = 0, c2 = 0, c3 = 0, c4 = 0;
#pragma unroll
    for (int i = 0; i < 8; ++i) {
      int c = hand_cards[b * 8 + i];
      int v = (c == 0) ? 0 : ((c - 1) % 13 + 1);
      int s = (c == 0) ? 0 : ((c - 1) / 13 + 1);
      aces += (v == 1);
      faces += (v >= 11 && v <= 13);
      low += (v >= 2 && v <= 6);
      c1 += (s == 1); c2 += (s == 2); c3 += (s == 3); c4 += (s == 4);
    }
    float sdiv = (float)((c1 > 0) + (c2 > 0) + (c3 > 0) + (c4 > 0)) * 0.25f;
    float hvr = (float)faces / (hsz + 1e-8f);
    bufB[(10 + 0) * 64 + r] = hsz;          bufB[(10 + 1) * 64 + r] = (float)aces;
    bufB[(10 + 2) * 64 + r] = (float)faces; bufB[(10 + 3) * 64 + r] = (float)low;
    bufB[(10 + 4) * 64 + r] = (float)c1;    bufB[(10 + 5) * 64 + r] = (float)c2;
    bufB[(10 + 6) * 64 + r] = (float)c3;    bufB[(10 + 7) * 64 + r] = (float)c4;
    bufB[(10 + 8) * 64 + r] = hvr;          bufB[(10 + 9) * 64 + r] = sdiv;
  }
  if (wq == 1) {                                            // enemy (quad) + sLen
    const int b = b0 + r;
    bufB[116 * 64 + r] = 8.0f / fmaxf((float)hand_size[b], 1.0f);
    float e[32];
    encode_card32(enemy_card[b], val_emb, suit_emb, type_emb, e);
#pragma unroll
    for (int g = 0; g < 8; ++g) {
      float4 ev = make_float4(e[g * 4], e[g * 4 + 1], e[g * 4 + 2], e[g * 4 + 3]);
      *(float4*)&bufA[(8 + g) * 256 + r * 4] = ev;   // cols 32..63
    }
  }
  __syncthreads();

  // ---------------- P1: se L1 20->64 relu: bufB[0:20) -> bufB rows[20:84) ---
  layerU<20, 4, true, true, false, false>(bufB, 0, bufB, 20, se_w1, 64, wq * 4,
                                          se_b1, r);
  __syncthreads();

  // ---------------- P2: strat_ctx -> bufA cols[64:96);  V -> bufB rows[84:116)
  layerU<64, 2, false, true, false, true>(bufB, 20, bufA, 64, se_w2, 32, wq * 2,
                                          se_b2, r);
  layerU<32, 2, false, true, true, false>(bufA, 32, bufB, 84, he_wv, 32, wq * 2,
                                          he_bv, r);
  __syncthreads();

  // ---------------- P3: hand_ctx = (V@wo + bo) * 8/len -> bufA cols[0:32) ---
  {
    const int j0 = wq * 2;
    float acc0 = he_bo[j0], acc1 = he_bo[j0 + 1];
#pragma unroll 4
    for (int k = 0; k < 32; ++k) {
      float a = bufB[(84 + k) * 64 + r];
      const float* wr = he_wo + (size_t)k * 32 + j0;
      acc0 += a * wr[0];
      acc1 += a * wr[1];
    }
    float scale = bufB[116 * 64 + r];
    bufA[QOFF(j0, r)] = scale * acc0;
    bufA[QOFF(j0 + 1, r)] = scale * acc1;
  }
  __syncthreads();

  // ---------------- L1: 150->128 relu (96 quad cols + 54 discard global) ----
  {
    const int j0 = wq * 8;
    float acc[8];
#pragma unroll
    for (int j = 0; j < 8; ++j) acc[j] = cx_b1[j0 + j];
#pragma unroll 4
    for (int g = 0; g < 24; ++g) {
      float4 a = *(const float4*)&bufA[g * 256 + r * 4];
#pragma unroll
      for (int q = 0; q < 4; ++q) {
        float av = (q == 0) ? a.x : (q == 1) ? a.y : (q == 2) ? a.z : a.w;
        const float* wr = cx_w1 + (size_t)(g * 4 + q) * 128 + j0;
#pragma unroll
        for (int j = 0; j < 8; ++j) acc[j] += av * wr[j];
      }
    }
    const float* drow = discard + (size_t)(b0 + r) * 54;
#pragma unroll 2
    for (int k = 0; k < 54; ++k) {
      float a = drow[k];
      const float* wr = cx_w1 + (size_t)(96 + k) * 128 + j0;
#pragma unroll
      for (int j = 0; j < 8; ++j) acc[j] += a * wr[j];
    }
    float4 o0 = make_float4(fmaxf(acc[0], 0.f), fmaxf(acc[1], 0.f),
                            fmaxf(acc[2], 0.f), fmaxf(acc[3], 0.f));
    float4 o1 = make_float4(fmaxf(acc[4], 0.f), fmaxf(acc[5], 0.f),
                            fmaxf(acc[6], 0.f), fmaxf(acc[7], 0.f));
    *(float4*)&bufB[(j0 >> 2) * 256 + r * 4] = o0;        // h1 quad
    *(float4*)&bufB[((j0 >> 2) + 1) * 256 + r * 4] = o1;
  }
  __syncthreads();

  // ---------------- L2: 128->128 relu  (bufB quad -> bufA quad) -------------
  layerU<128, 8, true, true, true, true>(bufB, 0, bufA, 0, cx_w2, 128, wq * 8,
                                         cx_b2, r);
  __syncthreads();

  // ---------------- L3: 128->128 (ctx)  (bufA quad -> bufB quad) ------------
  layerU<128, 8, false, true, true, true>(bufA, 0, bufB, 0, cx_w3, 128, wq * 8,
                                          cx_b3, r);
  __syncthreads();

  // ---------------- P7: t1 (waves 0-7) | P (waves 8-15)  (bufB -> bufA) -----
  if (wq < 8) {
    layerU<128, 8, true, true, true, true>(bufB, 0, bufA, 0, atc_w1, 64, wq * 8,
                                           atc_b1, r);
  } else {
    layerU<128, 8, false, false, true, true>(bufB, 0, bufA, 64, as_w1, 64,
                                             (wq - 8) * 8, nullptr, r);
  }
  __syncthreads();

  // ---------------- P8: 4 type logits (wave wq<4 computes logit wq) ---------
  if (wq < 4) {
    float acc = atc_b2[wq];
#pragma unroll 4
    for (int g = 0; g < 16; ++g) {                 // t1 = bufA quad groups 0..15
      float4 t = *(const float4*)&bufA[g * 256 + r * 4];
      acc += t.x * atc_w2[(g * 4 + 0) * 4 + wq];
      acc += t.y * atc_w2[(g * 4 + 1) * 4 + wq];
      acc += t.z * atc_w2[(g * 4 + 2) * 4 + wq];
      acc += t.w * atc_w2[(g * 4 + 3) * 4 + wq];
    }
    bufB[wq * 64 + r] = acc;   // overwrites dead ctx quad group 0
  }
  __syncthreads();

  // ---------------- P9: scoring. waves 0-14 -> 2 actions each ---------------
  if (wq < 15) {
    float l0 = bufB[0 * 64 + r], l1 = bufB[1 * 64 + r];
    float l2 = bufB[2 * 64 + r], l3 = bufB[3 * 64 + r];
    float m = fmaxf(fmaxf(l0, l1), fmaxf(l2, l3));
    float e0 = expf(l0 - m), e1 = expf(l1 - m), e2 = expf(l2 - m), e3 = expf(l3 - m);
    float inv = 1.f / (e0 + e1 + e2 + e3);
    float tp0 = e0 * inv, tp1 = e1 * inv, tp3 = e3 * inv;

    const float b3v = as_b3[0];
#pragma unroll 1
    for (int i = 0; i < 2; ++i) {
      const int a = wq * 2 + i;                // wave-uniform
      const float* qa = ws + a * 64;           // uniform -> s_load
      float acc[32];
#pragma unroll
      for (int j = 0; j < 32; ++j) acc[j] = 0.f;
#pragma unroll 2
      for (int g = 0; g < 16; ++g) {           // P = bufA quad groups 16..31
        float4 pv = *(const float4*)&bufA[(16 + g) * 256 + r * 4];
#pragma unroll
        for (int q = 0; q < 4; ++q) {
          float p = (q == 0) ? pv.x : (q == 1) ? pv.y : (q == 2) ? pv.z : pv.w;
          const int k = g * 4 + q;
          float s = fmaxf(p + qa[k], 0.f);
          const float* w2r = as_w2 + (size_t)k * 32;
#pragma unroll
          for (int j = 0; j < 32; ++j) acc[j] += s * w2r[j];
        }
      }
      float sc = b3v;
#pragma unroll
      for (int j = 0; j < 32; ++j)
        sc += fmaxf(acc[j] + as_b2[j], 0.f) * as_w3[j];
      float st = ws[1920 + a], hv = ws[1950 + a];
      float bon = (hv > 0.5f) ? (tp0 * st + tp1 * (1.f - st)) : tp3 * 2.f;
      out[(size_t)(b0 + r) * 30 + a] = sc + bon;
    }
  }
}

// ---------------------------------------------------------------------------
extern "C" void kernel_launch(void* const* d_in, const int* in_sizes, int n_in,
                              void* d_out, int out_size, void* d_ws, size_t ws_size,
                              hipStream_t stream) {
  (void)in_sizes; (void)n_in; (void)out_size; (void)ws_size;
  const int* hand_cards = (const int*)d_in[0];
  const int* enemy_card = (const int*)d_in[1];
  const int* hand_size = (const int*)d_in[2];
  const float* game_state = (const float*)d_in[3];
  const float* discard = (const float*)d_in[4];
  const int* acards = (const int*)d_in[5];
  // d_in[6] = num_valid_actions (unused scalar)
  const float* val_emb = (const float*)d_in[7];
  const float* suit_emb = (const float*)d_in[8];
  const float* type_emb = (const float*)d_in[9];
  const float* ce_w1 = (const float*)d_in[10], * ce_b1 = (const float*)d_in[11];
  const float* ce_w2 = (const float*)d_in[12], * ce_b2 = (const float*)d_in[13];
  // d_in[14..21] = ha_* (hand self-attention) -- provably dead code, unused
  const float* he_wv = (const float*)d_in[26], * he_bv = (const float*)d_in[27];
  const float* he_wo = (const float*)d_in[28], * he_bo = (const float*)d_in[29];
  const float* se_w1 = (const float*)d_in[30], * se_b1 = (const float*)d_in[31];
  const float* se_w2 = (const float*)d_in[32], * se_b2 = (const float*)d_in[33];
  const float* atc_w1 = (const float*)d_in[34], * atc_b1 = (const float*)d_in[35];
  const float* atc_w2 = (const float*)d_in[36], * atc_b2 = (const float*)d_in[37];
  const float* as_w1 = (const float*)d_in[38], * as_b1 = (const float*)d_in[39];
  const float* as_w2 = (const float*)d_in[40], * as_b2 = (const float*)d_in[41];
  const float* as_w3 = (const float*)d_in[42], * as_b3 = (const float*)d_in[43];
  const float* cx_w1 = (const float*)d_in[44], * cx_b1 = (const float*)d_in[45];
  const float* cx_w2 = (const float*)d_in[46], * cx_b2 = (const float*)d_in[47];
  const float* cx_w3 = (const float*)d_in[48], * cx_b3 = (const float*)d_in[49];
  float* ws = (float*)d_ws;
  float* out = (float*)d_out;

  hipLaunchKernelGGL(action_kernel, dim3(1), dim3(64), 0, stream,
                     acards, val_emb, suit_emb, type_emb,
                     ce_w1, ce_b1, ce_w2, ce_b2, as_w1, as_b1, ws);
  hipLaunchKernelGGL(policy_main, dim3(256), dim3(1024), 0, stream,
                     hand_cards, enemy_card, hand_size, game_state, discard,
                     val_emb, suit_emb, type_emb,
                     he_wv, he_bv, he_wo, he_bo,
                     se_w1, se_b1, se_w2, se_b2,
                     atc_w1, atc_b1, atc_w2, atc_b2,
                     as_w1, as_w2, as_b2, as_w3, as_b3,
                     cx_w1, cx_b1, cx_w2, cx_b2, cx_w3, cx_b3,
                     ws, out);
}